// Round 5
// baseline (1440.256 us; speedup 1.0000x reference)
//
#include <hip/hip_runtime.h>
#include <math.h>

typedef short short8 __attribute__((ext_vector_type(8)));
typedef float f32x4 __attribute__((ext_vector_type(4)));
typedef unsigned short ushort_t;

#define SCHUNK 1024

__device__ __forceinline__ ushort_t f2bf(float f) {  // RNE f32->bf16
  unsigned u = __float_as_uint(f);
  u += 0x7FFF + ((u >> 16) & 1);
  return (ushort_t)(u >> 16);
}
__device__ __forceinline__ float bf2f(ushort_t s) { return __uint_as_float(((unsigned)s) << 16); }
__device__ __forceinline__ float lrelu(float v) { return v > 0.f ? v : 0.2f * v; }

// ---------------- degree count (3 relations via blockIdx.y) ----------------
__global__ void k_count(const int* __restrict__ ei0, const int* __restrict__ ei1,
                        const int* __restrict__ ei2, int* __restrict__ cnt, int E, int N_) {
  int e = blockIdx.x * 256 + threadIdx.x;
  if (e >= E) return;
  const int r = blockIdx.y;
  const int* ei = (r == 0) ? ei0 : (r == 1) ? ei1 : ei2;
  atomicAdd(&cnt[r * N_ + ei[E + e]], 1);
}

// ---------------- two-level exclusive scan of cnt[0..M) ----------------
__global__ __launch_bounds__(256) void k_scanA(const int* __restrict__ cnt,
                                               int* __restrict__ bsum, int M) {
  __shared__ int sh[256];
  const int t = threadIdx.x;
  const int base = blockIdx.x * SCHUNK + t * 4;
  int s = 0;
  #pragma unroll
  for (int j = 0; j < 4; ++j) { int id = base + j; if (id < M) s += cnt[id]; }
  sh[t] = s;
  __syncthreads();
  for (int o = 128; o; o >>= 1) { if (t < o) sh[t] += sh[t + o]; __syncthreads(); }
  if (t == 0) bsum[blockIdx.x] = sh[0];
}

__global__ void k_scanB(int* __restrict__ bsum, int nblk, int* __restrict__ off, int M) {
  if (threadIdx.x == 0 && blockIdx.x == 0) {
    int run = 0;
    for (int b = 0; b < nblk; ++b) { int tv = bsum[b]; bsum[b] = run; run += tv; }
    off[M] = run;
  }
}

__global__ __launch_bounds__(256) void k_scanC(int* __restrict__ cntoff,
                                               const int* __restrict__ boff,
                                               int* __restrict__ wpos, int M) {
  __shared__ int sh[256];
  const int t = threadIdx.x;
  const int base = blockIdx.x * SCHUNK + t * 4;
  int v[4]; int s = 0;
  #pragma unroll
  for (int j = 0; j < 4; ++j) { int id = base + j; v[j] = (id < M) ? cntoff[id] : 0; s += v[j]; }
  sh[t] = s;
  __syncthreads();
  for (int o = 1; o < 256; o <<= 1) {
    int xv = (t >= o) ? sh[t - o] : 0;
    __syncthreads();
    sh[t] += xv;
    __syncthreads();
  }
  int excl = boff[blockIdx.x] + sh[t] - s;
  #pragma unroll
  for (int j = 0; j < 4; ++j) {
    int id = base + j;
    if (id < M) { cntoff[id] = excl; wpos[id] = excl; excl += v[j]; }
  }
}

// ---------------- CSR fill ----------------
__global__ void k_fill(const int* __restrict__ ei0, const int* __restrict__ ei1,
                       const int* __restrict__ ei2, int* __restrict__ wpos,
                       int* __restrict__ srcs, int E, int N_) {
  int e = blockIdx.x * 256 + threadIdx.x;
  if (e >= E) return;
  const int r = blockIdx.y;
  const int* ei = (r == 0) ? ei0 : (r == 1) ? ei1 : ei2;
  const int src = ei[e], dst = ei[E + e];
  const int p = atomicAdd(&wpos[r * N_ + dst], 1);
  srcs[p] = src;
}

// ---------------- geo distance sum over ei_mol ----------------
__global__ void k_geo(const float* __restrict__ pos, const int* __restrict__ ei,
                      float* gsum, int E) {
  int e = blockIdx.x * 256 + threadIdx.x;
  float d = 0.f;
  if (e < E) {
    int r = ei[e], c = ei[E + e];
    float dx = pos[3*r]   - pos[3*c];
    float dy = pos[3*r+1] - pos[3*c+1];
    float dz = pos[3*r+2] - pos[3*c+2];
    d = sqrtf(dx*dx + dy*dy + dz*dz);
  }
  #pragma unroll
  for (int o = 32; o; o >>= 1) d += __shfl_down(d, o);
  if ((threadIdx.x & 63) == 0) atomicAdd(gsum, d);
}

// ---------------- stage1: dense weight products + bias/csum vectors ----------------
// W''_L (128x24): slot = rel*8 + isD*4 + head ; WmWl_L (128x128, for CL only)
// BL = bc+bd+bl+bm@Wl ; CL = colsum(WmWl)
// BV_P[160]=[bp | bp@W''_0 | 0]; CV_P[160]=[0 | 0 | colsum(W''_0 mol cols)]
// CV1[416]: 0 except [400..407] = colsum(W''_1 mol cols)  (layer-2 alpha cshift)
struct S1Args {
  const float *Wc[2], *as_c[2], *ad_c[2], *bc[2];
  const float *Wd[2], *as_d[2], *ad_d[2], *bd[2];
  const float *Wm[2], *as_m[2], *ad_m[2], *bm[2];
  const float *Wl[2], *bl[2];
  const float *bp;
  float *WPP[2], *WMWL[2];
  float *BL[2], *CL[2];
  float *BV_P, *CV_P, *CV1;
};
__global__ __launch_bounds__(256) void k_stage1(S1Args a) {
  const int L = blockIdx.x;
  const int t = threadIdx.x;
  for (int idx = t; idx < 128 * 24; idx += 256) {
    int k = idx / 24, slot = idx % 24;
    int rel = slot >> 3, inner = slot & 7, h = inner & 3, isD = inner >> 2;
    const float *W, *av;
    int fh, heads;
    if (rel == 0)      { W = a.Wc[L]; av = isD ? a.ad_c[L] : a.as_c[L]; fh = 64; heads = 2; }
    else if (rel == 1) { W = a.Wd[L]; av = isD ? a.ad_d[L] : a.as_d[L]; fh = 64; heads = 2; }
    else               { W = a.Wm[L]; av = isD ? a.ad_m[L] : a.as_m[L]; fh = 32; heads = 4; }
    float s = 0.f;
    if (h < heads)
      for (int f = 0; f < fh; ++f) s += W[k * 128 + h * fh + f] * av[h * fh + f];
    a.WPP[L][idx] = s;
  }
  for (int idx = t; idx < 128 * 128; idx += 256) {
    int k = idx >> 7, c = idx & 127;
    float s = 0.f;
    for (int j = 0; j < 128; ++j) s += a.Wm[L][k * 128 + j] * a.Wl[L][j * 128 + c];
    a.WMWL[L][idx] = s;
  }
  __syncthreads();
  if (t < 128) {
    float cs = 0.f, bw = 0.f;
    for (int k = 0; k < 128; ++k) {
      cs += a.WMWL[L][k * 128 + t];
      bw += a.bm[L][k] * a.Wl[L][k * 128 + t];
    }
    a.CL[L][t] = cs;
    a.BL[L][t] = a.bc[L][t] + a.bd[L][t] + a.bl[L][t] + bw;
  }
  if (L == 0) {
    if (t < 160) {
      float b = 0.f, c = 0.f;
      if (t < 128) b = a.bp[t];
      else if (t < 152) {
        int e = t - 128;
        for (int k = 0; k < 128; ++k) b += a.bp[k] * a.WPP[0][k * 24 + e];
        if (e >= 16) for (int k = 0; k < 128; ++k) c += a.WPP[0][k * 24 + e];
      }
      a.BV_P[t] = b; a.CV_P[t] = c;
    }
  } else {
    for (int t2 = t; t2 < 416; t2 += 256) {
      float c = 0.f;
      if (t2 >= 400 && t2 < 408) {
        const int slot = t2 - 384;   // 16..23 (mol aS+aD)
        for (int k = 0; k < 128; ++k) c += a.WPP[1][k * 24 + slot];
      }
      a.CV1[t2] = c;
    }
  }
}

// ---------------- stage2: EXT_P = Wp @ W''_0  (128x24) ----------------
__global__ __launch_bounds__(256) void k_stage2(const float* __restrict__ Wp,
                                                const float* __restrict__ WPP0,
                                                float* __restrict__ EXT_P) {
  for (int idx = threadIdx.x; idx < 128 * 24; idx += 256) {
    int k = idx / 24, c = idx % 24;
    float s = 0.f;
    for (int j = 0; j < 128; ++j) s += Wp[k * 128 + j] * WPP0[j * 24 + c];
    EXT_P[idx] = s;
  }
}

// ---------------- pack dense -> MFMA fragment images (hi/lo bf16) ----------------
// idx = (tile*64+lane)*8+j ; tile = nt*nkt+kt ; k = kt*32+(lane>>4)*8+j ; col = nt*16+(lane&15)
// img0: proj [Wp | EXT_P] 10nt,4kt   img1: [W1c|W1d|W1m] 24nt,4kt
// img2: [W2c|W2d|W2m|WPP1|0] 26nt,4kt   img3/4: [I128 ; Wl] 8nt,8kt
struct PackArgs {
  const float *Wp, *EXT_P;
  const float *W1c, *W1d, *W1m;
  const float *W2c, *W2d, *W2m, *WPP1;
  const float *Wl1, *Wl2;
  ushort_t *hi[5], *lo[5];
};
__global__ __launch_bounds__(256) void k_pack(PackArgs p) {
  const int img = blockIdx.x;
  const int nkt = (img >= 3) ? 8 : 4;
  const int nnt = (img == 0) ? 10 : ((img == 1) ? 24 : ((img == 2) ? 26 : 8));
  const int nfrag = nnt * nkt * 512;
  for (int idx = threadIdx.x; idx < nfrag; idx += 256) {
    int j = idx & 7, lane = (idx >> 3) & 63;
    int kt = (idx >> 9) % nkt, nt = (idx >> 9) / nkt;
    int k = kt * 32 + (lane >> 4) * 8 + j;
    int col = nt * 16 + (lane & 15);
    float w = 0.f;
    if (img == 0) {
      if (col < 128) w = p.Wp[k * 128 + col];
      else if (col < 152) w = p.EXT_P[k * 24 + col - 128];
    } else if (img == 1) {
      if (col < 128)      w = p.W1c[k * 128 + col];
      else if (col < 256) w = p.W1d[k * 128 + col - 128];
      else                w = p.W1m[k * 128 + col - 256];
    } else if (img == 2) {
      if (col < 128)      w = p.W2c[k * 128 + col];
      else if (col < 256) w = p.W2d[k * 128 + col - 128];
      else if (col < 384) w = p.W2m[k * 128 + col - 256];
      else if (col < 408) w = p.WPP1[k * 24 + col - 384];
    } else {
      const float* Wl = (img == 3) ? p.Wl1 : p.Wl2;
      if (k < 128) w = (k == col) ? 1.f : 0.f;
      else         w = Wl[(k - 128) * 128 + col];
    }
    ushort_t h = f2bf(w);
    p.hi[img][idx] = h;
    p.lo[img][idx] = f2bf(w - bf2f(h));
  }
}

// ---------------- proj GEMM: f32 A split-bf16, K=128, C f32 + 24 alpha cols ----------
template <int NNT, int NCMAIN>
__global__ __launch_bounds__(256, 2) void k_gmm(
    const float* __restrict__ A, const ushort_t* __restrict__ HI,
    const ushort_t* __restrict__ LO, const float* __restrict__ biasv,
    const float* __restrict__ csumv, const float* __restrict__ gsum, float gscale,
    float* __restrict__ C, float* __restrict__ ALPHA, int n)
{
  const int wave = threadIdx.x >> 6, lane = threadIdx.x & 63;
  const int m = lane & 15, kq = lane >> 4;
  const float cb = gscale * gsum[0];
  const int rw = blockIdx.x * 128 + wave * 32;

  short8 ah[2][4], al[2][4];
  #pragma unroll
  for (int sub = 0; sub < 2; ++sub) {
    const int row = rw + sub * 16 + m;
    const bool ok = row < n;
    const float* ap = A + (size_t)row * 128 + kq * 8;
    #pragma unroll
    for (int kt = 0; kt < 4; ++kt) {
      f32x4 x0 = {0.f, 0.f, 0.f, 0.f}, x1 = {0.f, 0.f, 0.f, 0.f};
      if (ok) { x0 = *(const f32x4*)(ap + kt * 32); x1 = *(const f32x4*)(ap + kt * 32 + 4); }
      #pragma unroll
      for (int j = 0; j < 4; ++j) {
        ushort_t h0 = f2bf(x0[j]);
        ah[sub][kt][j] = (short)h0;
        al[sub][kt][j] = (short)f2bf(x0[j] - bf2f(h0));
        ushort_t h1 = f2bf(x1[j]);
        ah[sub][kt][4 + j] = (short)h1;
        al[sub][kt][4 + j] = (short)f2bf(x1[j] - bf2f(h1));
      }
    }
  }
  f32x4 acc[2][NNT];
  #pragma unroll
  for (int sub = 0; sub < 2; ++sub)
    #pragma unroll
    for (int nt = 0; nt < NNT; ++nt) acc[sub][nt] = f32x4{0.f, 0.f, 0.f, 0.f};

  #pragma unroll
  for (int nt = 0; nt < NNT; ++nt) {
    #pragma unroll
    for (int kt = 0; kt < 4; ++kt) {
      const int fo = ((nt * 4 + kt) * 64 + lane) * 8;
      const short8 bh = *(const short8*)&HI[fo];
      const short8 bl = *(const short8*)&LO[fo];
      #pragma unroll
      for (int sub = 0; sub < 2; ++sub) {
        acc[sub][nt] = __builtin_amdgcn_mfma_f32_16x16x32_bf16(ah[sub][kt], bh, acc[sub][nt], 0, 0, 0);
        acc[sub][nt] = __builtin_amdgcn_mfma_f32_16x16x32_bf16(al[sub][kt], bh, acc[sub][nt], 0, 0, 0);
        acc[sub][nt] = __builtin_amdgcn_mfma_f32_16x16x32_bf16(ah[sub][kt], bl, acc[sub][nt], 0, 0, 0);
      }
    }
  }
  #pragma unroll
  for (int sub = 0; sub < 2; ++sub) {
    const int rbase = rw + sub * 16 + kq * 4;
    #pragma unroll
    for (int nt = 0; nt < NNT; ++nt) {
      const int col = nt * 16 + m;
      const float add = biasv[col] + cb * csumv[col];
      #pragma unroll
      for (int r = 0; r < 4; ++r) {
        const float v = acc[sub][nt][r] + add;
        const int row = rbase + r;
        if (col < NCMAIN) C[(size_t)row * 128 + col] = v;
        else {
          const int ai = col - NCMAIN;
          if (ai < 24) ALPHA[(size_t)row * 24 + ai] = v;
        }
      }
    }
  }
}

// ---------------- GEMM1: f32 A split-bf16, K=128, bf16 C (HT) + alpha cols ----------
// 16 rows/wave, 64 rows/block. csumv indexed by global col (>=416 entries).
template <int NNT, int NCMAIN>
__global__ __launch_bounds__(256, 2) void k_gmmA16(
    const float* __restrict__ A, const ushort_t* __restrict__ HI,
    const ushort_t* __restrict__ LO,
    const float* __restrict__ csumv, const float* __restrict__ gsum, float gscale,
    ushort_t* __restrict__ C16, float* __restrict__ ALPHA, int n)
{
  const int wave = threadIdx.x >> 6, lane = threadIdx.x & 63;
  const int m = lane & 15, kq = lane >> 4;
  const int rw = blockIdx.x * 64 + wave * 16;
  const int row = rw + m;
  const bool ok = row < n;
  const float* ap = A + (size_t)row * 128 + kq * 8;

  short8 ah[4], al[4];
  #pragma unroll
  for (int kt = 0; kt < 4; ++kt) {
    f32x4 x0 = {0.f, 0.f, 0.f, 0.f}, x1 = {0.f, 0.f, 0.f, 0.f};
    if (ok) { x0 = *(const f32x4*)(ap + kt * 32); x1 = *(const f32x4*)(ap + kt * 32 + 4); }
    #pragma unroll
    for (int j = 0; j < 4; ++j) {
      ushort_t h0 = f2bf(x0[j]);
      ah[kt][j] = (short)h0;
      al[kt][j] = (short)f2bf(x0[j] - bf2f(h0));
      ushort_t h1 = f2bf(x1[j]);
      ah[kt][4 + j] = (short)h1;
      al[kt][4 + j] = (short)f2bf(x1[j] - bf2f(h1));
    }
  }
  f32x4 acc[NNT];
  #pragma unroll
  for (int nt = 0; nt < NNT; ++nt) acc[nt] = f32x4{0.f, 0.f, 0.f, 0.f};

  #pragma unroll
  for (int nt = 0; nt < NNT; ++nt) {
    #pragma unroll
    for (int kt = 0; kt < 4; ++kt) {
      const int fo = ((nt * 4 + kt) * 64 + lane) * 8;
      const short8 bh = *(const short8*)&HI[fo];
      const short8 bl = *(const short8*)&LO[fo];
      acc[nt] = __builtin_amdgcn_mfma_f32_16x16x32_bf16(ah[kt], bh, acc[nt], 0, 0, 0);
      acc[nt] = __builtin_amdgcn_mfma_f32_16x16x32_bf16(al[kt], bh, acc[nt], 0, 0, 0);
      acc[nt] = __builtin_amdgcn_mfma_f32_16x16x32_bf16(ah[kt], bl, acc[nt], 0, 0, 0);
    }
  }
  const float cb = gscale * gsum[0];
  const int rbase = rw + kq * 4;
  #pragma unroll
  for (int nt = 0; nt < NNT; ++nt) {
    const int col = nt * 16 + m;
    const float add = cb * csumv[col];
    #pragma unroll
    for (int r = 0; r < 4; ++r) {
      const float v = acc[nt][r] + add;
      const int row2 = rbase + r;
      if (col < NCMAIN) {
        if (row2 < n) C16[(size_t)row2 * 384 + col] = f2bf(v);
      } else {
        const int ai = col - NCMAIN;
        if (ai < 24) ALPHA[(size_t)row2 * 24 + ai] = v;
      }
    }
  }
}

// ---------------- GEMM2: bf16 A (U, K=256), B=[I;Wl], +bias+cshift+ReLU, f32 C ------
__global__ __launch_bounds__(256, 2) void k_gmm2(
    const ushort_t* __restrict__ U16, const ushort_t* __restrict__ HI,
    const ushort_t* __restrict__ LO, const float* __restrict__ biasv,
    const float* __restrict__ csumv, const float* __restrict__ gsum, float gscale,
    float* __restrict__ C, int n)
{
  const int wave = threadIdx.x >> 6, lane = threadIdx.x & 63;
  const int m = lane & 15, kq = lane >> 4;
  const int rw = blockIdx.x * 256 + wave * 64;

  f32x4 acc[4][8];
  #pragma unroll
  for (int sub = 0; sub < 4; ++sub)
    #pragma unroll
    for (int nt = 0; nt < 8; ++nt) acc[sub][nt] = f32x4{0.f, 0.f, 0.f, 0.f};

  for (int kt = 0; kt < 8; ++kt) {
    short8 ah[4];
    #pragma unroll
    for (int sub = 0; sub < 4; ++sub) {
      const int row = rw + sub * 16 + m;
      short8 z = {0, 0, 0, 0, 0, 0, 0, 0};
      ah[sub] = (row < n) ? *(const short8*)(U16 + (size_t)row * 256 + kt * 32 + kq * 8) : z;
    }
    #pragma unroll
    for (int nt = 0; nt < 8; ++nt) {
      const int fo = ((nt * 8 + kt) * 64 + lane) * 8;
      const short8 bh = *(const short8*)&HI[fo];
      const short8 bl = *(const short8*)&LO[fo];
      #pragma unroll
      for (int sub = 0; sub < 4; ++sub) {
        acc[sub][nt] = __builtin_amdgcn_mfma_f32_16x16x32_bf16(ah[sub], bh, acc[sub][nt], 0, 0, 0);
        acc[sub][nt] = __builtin_amdgcn_mfma_f32_16x16x32_bf16(ah[sub], bl, acc[sub][nt], 0, 0, 0);
      }
    }
  }
  const float cb = gscale * gsum[0];
  #pragma unroll
  for (int sub = 0; sub < 4; ++sub) {
    const int rbase = rw + sub * 16 + kq * 4;
    #pragma unroll
    for (int nt = 0; nt < 8; ++nt) {
      const int col = nt * 16 + m;
      const float add = biasv[col] + cb * csumv[col];
      #pragma unroll
      for (int r = 0; r < 4; ++r)
        C[(size_t)(rbase + r) * 128 + col] = fmaxf(acc[sub][nt][r] + add, 0.f);
    }
  }
}

// ---------------- fused conv: per-head softmax aggregation of HT blocks -------------
// which=0 wave: chem+cond -> U[:,0:128] = Vc+Vd ; which=1 wave: mol -> U[:,128:256]
__device__ __forceinline__ float2 aggR(
    const ushort_t* __restrict__ HT, const float* __restrict__ ALPHA,
    const int* __restrict__ SRCS, const int* __restrict__ OFF,
    int i, int rel, int base, int shift, int c0, int N_)
{
  const int sb = rel * 8, hd = c0 >> shift;
  const float aSi = ALPHA[(size_t)i * 24 + sb + hd];
  const float aDi = ALPHA[(size_t)i * 24 + sb + 4 + hd];
  const int idx = rel * N_ + i;
  const int e0 = OFF[idx];
  const int deg = OFF[idx + 1] - e0;
  const int* sp = SRCS + e0;

  float mx = lrelu(aSi + aDi), z = 1.f;
  const ushort2 sh = *(const ushort2*)(HT + (size_t)i * 384 + base + c0);
  float a0 = bf2f(sh.x), a1 = bf2f(sh.y);
  for (int j = 0; j < deg; ++j) {
    const int s = sp[j];
    const float e = lrelu(ALPHA[(size_t)s * 24 + sb + hd] + aDi);
    const float mn = fmaxf(mx, e);
    const float f1 = __expf(mx - mn), f2 = __expf(e - mn);
    const ushort2 hv = *(const ushort2*)(HT + (size_t)s * 384 + base + c0);
    z = z * f1 + f2;
    a0 = a0 * f1 + f2 * bf2f(hv.x);
    a1 = a1 * f1 + f2 * bf2f(hv.y);
    mx = mn;
  }
  const float inv = 1.f / (z + 1e-16f);
  return float2{a0 * inv, a1 * inv};
}

__global__ __launch_bounds__(256) void k_fconv(
    const ushort_t* __restrict__ HT, const float* __restrict__ ALPHA,
    const int* __restrict__ SRCS, const int* __restrict__ OFF,
    ushort_t* __restrict__ U16, int N_)
{
  const int wid = blockIdx.x * 4 + (threadIdx.x >> 6);
  if (wid >= 2 * N_) return;
  const int i = wid >> 1;
  const int which = wid & 1;
  const int lane = threadIdx.x & 63;
  const int c0 = lane * 2;
  if (which == 0) {
    const float2 vc = aggR(HT, ALPHA, SRCS, OFF, i, 0, 0,   6, c0, N_);
    const float2 vd = aggR(HT, ALPHA, SRCS, OFF, i, 1, 128, 6, c0, N_);
    ushort_t* up = U16 + (size_t)i * 256 + c0;
    up[0] = f2bf(vc.x + vd.x);
    up[1] = f2bf(vc.y + vd.y);
  } else {
    const float2 vm = aggR(HT, ALPHA, SRCS, OFF, i, 2, 256, 5, c0, N_);
    ushort_t* up = U16 + (size_t)i * 256 + 128 + c0;
    up[0] = f2bf(vm.x);
    up[1] = f2bf(vm.y);
  }
}

// ---------------- output heads ----------------
__global__ __launch_bounds__(256) void k_head(
    const float* __restrict__ h2, const float* __restrict__ Wy, const float* __restrict__ by,
    const float* __restrict__ Wa, const float* __restrict__ ba,
    float* __restrict__ out, int n)
{
  const int r = blockIdx.x * 4 + (threadIdx.x >> 6);
  const int L = threadIdx.x & 63;
  if (r >= n) return;
  const float a = h2[(size_t)r * 128 + L];
  const float b = h2[(size_t)r * 128 + 64 + L];
  float py = a * Wy[L] + b * Wy[64 + L];
  float pa = a * Wa[L] + b * Wa[64 + L];
  #pragma unroll
  for (int o = 32; o; o >>= 1) { py += __shfl_down(py, o); pa += __shfl_down(pa, o); }
  if (L == 0) {
    out[(size_t)r * 2]     = py + by[0];
    out[(size_t)r * 2 + 1] = pa + ba[0];
  }
}

extern "C" void kernel_launch(void* const* d_in, const int* in_sizes, int n_in,
                              void* d_out, int out_size, void* d_ws, size_t ws_size,
                              hipStream_t stream) {
  const int N = in_sizes[0] / 128;
  const int E = in_sizes[2] / 2;
  const int npad = (N + 255) & ~255;
  const int M = 3 * N;

  const float* x       = (const float*)d_in[0];
  const float* pos     = (const float*)d_in[1];
  const int*   ei_chem = (const int*)d_in[2];
  const int*   ei_cond = (const int*)d_in[3];
  const int*   ei_mol  = (const int*)d_in[4];
  const float* Wp = (const float*)d_in[5];
  const float* Wy = (const float*)d_in[35];
  const float* by = (const float*)d_in[36];
  const float* Wa = (const float*)d_in[37];
  const float* ba = (const float*)d_in[38];

  char* ws = (char*)d_ws;
  size_t off = 0;
  auto alloc = [&](size_t bytes) -> void* {
    void* p = ws + off; off += (bytes + 255) & ~(size_t)255; return p;
  };
  float*    H     = (float*)alloc((size_t)npad * 128 * sizeof(float));     // h0/h1/h2
  ushort_t* HT    = (ushort_t*)alloc((size_t)N * 384 * sizeof(ushort_t)); // bf16 h@[Wc|Wd|Wm]
  ushort_t* U     = (ushort_t*)alloc((size_t)N * 256 * sizeof(ushort_t)); // bf16 [Vcd|Vm]
  float*    ALPHA = (float*)alloc((size_t)npad * 24 * sizeof(float));
  int*      OFF   = (int*)alloc((size_t)(M + 64) * sizeof(int));
  int*      WPOS  = (int*)alloc((size_t)M * sizeof(int));
  int*      SRCS  = (int*)alloc((size_t)3 * E * sizeof(int));
  const int nblk = (M + SCHUNK - 1) / SCHUNK;
  int*      BSUM  = (int*)alloc((size_t)nblk * sizeof(int));
  float*    GSUM  = (float*)alloc(256);

  float* WPP0  = (float*)alloc(128 * 24 * sizeof(float));
  float* WPP1  = (float*)alloc(128 * 24 * sizeof(float));
  float* WMWL0 = (float*)alloc(128 * 128 * sizeof(float));
  float* WMWL1 = (float*)alloc(128 * 128 * sizeof(float));
  float* EXT_P = (float*)alloc(128 * 24 * sizeof(float));
  float* BL0  = (float*)alloc(128 * sizeof(float));
  float* CL0  = (float*)alloc(128 * sizeof(float));
  float* BL1  = (float*)alloc(128 * sizeof(float));
  float* CL1  = (float*)alloc(128 * sizeof(float));
  float* BV_P = (float*)alloc(160 * sizeof(float));
  float* CV_P = (float*)alloc(160 * sizeof(float));
  float* CV1  = (float*)alloc(416 * sizeof(float));
  // fragment images: 0=proj 1=G1L1 2=G1L2 3=G2L1 4=G2L2
  const int isz[5] = {20480, 49152, 53248, 32768, 32768};
  ushort_t *HIs[5], *LOs[5];
  for (int s = 0; s < 5; ++s) {
    HIs[s] = (ushort_t*)alloc((size_t)isz[s] * 2);
    LOs[s] = (ushort_t*)alloc((size_t)isz[s] * 2);
  }

  hipMemsetAsync(OFF, 0, (size_t)(M + 1) * sizeof(int), stream);
  hipMemsetAsync(GSUM, 0, sizeof(float), stream);

  const int egrid = (E + 255) / 256;
  dim3 eg3(egrid, 3);
  k_count<<<eg3, 256, 0, stream>>>(ei_chem, ei_cond, ei_mol, OFF, E, N);
  k_geo<<<egrid, 256, 0, stream>>>(pos, ei_mol, GSUM, E);
  k_scanA<<<nblk, 256, 0, stream>>>(OFF, BSUM, M);
  k_scanB<<<1, 64, 0, stream>>>(BSUM, nblk, OFF, M);
  k_scanC<<<nblk, 256, 0, stream>>>(OFF, BSUM, WPOS, M);
  k_fill<<<eg3, 256, 0, stream>>>(ei_chem, ei_cond, ei_mol, WPOS, SRCS, E, N);

  S1Args s1{};
  for (int L = 0; L < 2; ++L) {
    const int b = (L == 0) ? 7 : 21;
    s1.Wc[L] = (const float*)d_in[b+0];  s1.as_c[L] = (const float*)d_in[b+1];
    s1.ad_c[L] = (const float*)d_in[b+2]; s1.bc[L] = (const float*)d_in[b+3];
    s1.Wd[L] = (const float*)d_in[b+4];  s1.as_d[L] = (const float*)d_in[b+5];
    s1.ad_d[L] = (const float*)d_in[b+6]; s1.bd[L] = (const float*)d_in[b+7];
    s1.Wm[L] = (const float*)d_in[b+8];  s1.as_m[L] = (const float*)d_in[b+9];
    s1.ad_m[L] = (const float*)d_in[b+10]; s1.bm[L] = (const float*)d_in[b+11];
    s1.Wl[L] = (const float*)d_in[b+12]; s1.bl[L] = (const float*)d_in[b+13];
  }
  s1.bp = (const float*)d_in[6];
  s1.WPP[0] = WPP0; s1.WPP[1] = WPP1; s1.WMWL[0] = WMWL0; s1.WMWL[1] = WMWL1;
  s1.BL[0] = BL0; s1.CL[0] = CL0; s1.BL[1] = BL1; s1.CL[1] = CL1;
  s1.BV_P = BV_P; s1.CV_P = CV_P; s1.CV1 = CV1;
  k_stage1<<<2, 256, 0, stream>>>(s1);
  k_stage2<<<1, 256, 0, stream>>>(Wp, WPP0, EXT_P);

  PackArgs pk{};
  pk.Wp = Wp; pk.EXT_P = EXT_P;
  pk.W1c = s1.Wc[0]; pk.W1d = s1.Wd[0]; pk.W1m = s1.Wm[0];
  pk.W2c = s1.Wc[1]; pk.W2d = s1.Wd[1]; pk.W2m = s1.Wm[1]; pk.WPP1 = WPP1;
  pk.Wl1 = s1.Wl[0]; pk.Wl2 = s1.Wl[1];
  for (int s = 0; s < 5; ++s) { pk.hi[s] = HIs[s]; pk.lo[s] = LOs[s]; }
  k_pack<<<5, 256, 0, stream>>>(pk);

  const float gscale = 0.1f / (float)E;
  const int g128  = npad / 128;
  const int g64   = (N + 63) / 64;
  const int g256  = npad / 256;
  const int gconv = (2 * N + 3) / 4;

  // h0 (+ layer-1 alphas) = x @ [Wp | Wp@W1''] + folds
  k_gmm<10, 128><<<g128, 256, 0, stream>>>(x, HIs[0], LOs[0], BV_P, CV_P, GSUM, gscale,
                                           H, ALPHA, N);
  // layer 1: HT = h0@[W1c|W1d|W1m] ; conv ; h1 = relu(Vcd + Vm@Wl1 + BL0 + c*CL0)
  k_gmmA16<24, 384><<<g64, 256, 0, stream>>>(H, HIs[1], LOs[1], CV1, GSUM, 0.f,
                                             HT, ALPHA, N);
  k_fconv<<<gconv, 256, 0, stream>>>(HT, ALPHA, SRCS, OFF, U, N);
  k_gmm2<<<g256, 256, 0, stream>>>(U, HIs[3], LOs[3], BL0, CL0, GSUM, gscale, H, N);
  // layer 2: HT = h1@[W2c|W2d|W2m] + layer-2 alphas (incl. mol cshift via CV1)
  k_gmmA16<26, 384><<<g64, 256, 0, stream>>>(H, HIs[2], LOs[2], CV1, GSUM, gscale,
                                             HT, ALPHA, N);
  k_fconv<<<gconv, 256, 0, stream>>>(HT, ALPHA, SRCS, OFF, U, N);
  k_gmm2<<<g256, 256, 0, stream>>>(U, HIs[4], LOs[4], BL1, CL1, GSUM, gscale, H, N);

  k_head<<<(N + 3) / 4, 256, 0, stream>>>(H, Wy, by, Wa, ba, (float*)d_out, N);
}

// Round 6
// 1153.576 us; speedup vs baseline: 1.2485x; 1.2485x over previous
//
#include <hip/hip_runtime.h>
#include <math.h>

typedef short short8 __attribute__((ext_vector_type(8)));
typedef float f32x4 __attribute__((ext_vector_type(4)));
typedef unsigned short ushort_t;

#define SCHUNK 1024

__device__ __forceinline__ ushort_t f2bf(float f) {  // RNE f32->bf16
  unsigned u = __float_as_uint(f);
  u += 0x7FFF + ((u >> 16) & 1);
  return (ushort_t)(u >> 16);
}
__device__ __forceinline__ float bf2f(ushort_t s) { return __uint_as_float(((unsigned)s) << 16); }
__device__ __forceinline__ float lrelu(float v) { return v > 0.f ? v : 0.2f * v; }

// ---------------- degree count (3 relations via blockIdx.y) ----------------
__global__ void k_count(const int* __restrict__ ei0, const int* __restrict__ ei1,
                        const int* __restrict__ ei2, int* __restrict__ cnt, int E, int N_) {
  int e = blockIdx.x * 256 + threadIdx.x;
  if (e >= E) return;
  const int r = blockIdx.y;
  const int* ei = (r == 0) ? ei0 : (r == 1) ? ei1 : ei2;
  atomicAdd(&cnt[r * N_ + ei[E + e]], 1);
}

// ---------------- two-level exclusive scan of cnt[0..M) ----------------
__global__ __launch_bounds__(256) void k_scanA(const int* __restrict__ cnt,
                                               int* __restrict__ bsum, int M) {
  __shared__ int sh[256];
  const int t = threadIdx.x;
  const int base = blockIdx.x * SCHUNK + t * 4;
  int s = 0;
  #pragma unroll
  for (int j = 0; j < 4; ++j) { int id = base + j; if (id < M) s += cnt[id]; }
  sh[t] = s;
  __syncthreads();
  for (int o = 128; o; o >>= 1) { if (t < o) sh[t] += sh[t + o]; __syncthreads(); }
  if (t == 0) bsum[blockIdx.x] = sh[0];
}

// parallel single-block scan of block sums (nblk <= 512)
__global__ __launch_bounds__(512) void k_scanB(int* __restrict__ bsum, int nblk,
                                               int* __restrict__ off, int M) {
  __shared__ int sh[512];
  const int t = threadIdx.x;
  const int v = (t < nblk) ? bsum[t] : 0;
  sh[t] = v;
  __syncthreads();
  for (int o = 1; o < 512; o <<= 1) {
    int xv = (t >= o) ? sh[t - o] : 0;
    __syncthreads();
    sh[t] += xv;
    __syncthreads();
  }
  if (t < nblk) bsum[t] = sh[t] - v;   // exclusive
  if (t == 511) off[M] = sh[511];
}

__global__ __launch_bounds__(256) void k_scanC(int* __restrict__ cntoff,
                                               const int* __restrict__ boff,
                                               int* __restrict__ wpos, int M) {
  __shared__ int sh[256];
  const int t = threadIdx.x;
  const int base = blockIdx.x * SCHUNK + t * 4;
  int v[4]; int s = 0;
  #pragma unroll
  for (int j = 0; j < 4; ++j) { int id = base + j; v[j] = (id < M) ? cntoff[id] : 0; s += v[j]; }
  sh[t] = s;
  __syncthreads();
  for (int o = 1; o < 256; o <<= 1) {
    int xv = (t >= o) ? sh[t - o] : 0;
    __syncthreads();
    sh[t] += xv;
    __syncthreads();
  }
  int excl = boff[blockIdx.x] + sh[t] - s;
  #pragma unroll
  for (int j = 0; j < 4; ++j) {
    int id = base + j;
    if (id < M) { cntoff[id] = excl; wpos[id] = excl; excl += v[j]; }
  }
}

// ---------------- CSR fill ----------------
__global__ void k_fill(const int* __restrict__ ei0, const int* __restrict__ ei1,
                       const int* __restrict__ ei2, int* __restrict__ wpos,
                       int* __restrict__ srcs, int E, int N_) {
  int e = blockIdx.x * 256 + threadIdx.x;
  if (e >= E) return;
  const int r = blockIdx.y;
  const int* ei = (r == 0) ? ei0 : (r == 1) ? ei1 : ei2;
  const int src = ei[e], dst = ei[E + e];
  const int p = atomicAdd(&wpos[r * N_ + dst], 1);
  srcs[p] = src;
}

// ---------------- geo distance sum over ei_mol ----------------
__global__ void k_geo(const float* __restrict__ pos, const int* __restrict__ ei,
                      float* gsum, int E) {
  int e = blockIdx.x * 256 + threadIdx.x;
  float d = 0.f;
  if (e < E) {
    int r = ei[e], c = ei[E + e];
    float dx = pos[3*r]   - pos[3*c];
    float dy = pos[3*r+1] - pos[3*c+1];
    float dz = pos[3*r+2] - pos[3*c+2];
    d = sqrtf(dx*dx + dy*dy + dz*dz);
  }
  #pragma unroll
  for (int o = 32; o; o >>= 1) d += __shfl_down(d, o);
  if ((threadIdx.x & 63) == 0) atomicAdd(gsum, d);
}

// ---------------- stage1: dense weight products + bias/csum vectors ----------------
// W''_L (128x24): slot = rel*8 + isD*4 + head
// CL = colsum(Wm@Wl) = colsum(Wm)@Wl   (O(128^2), no WmWl materialization)
// BL = bc+bd+bl+bm@Wl
// BV_P[160]=[bp | bp@W''_0 | 0]; CV_P[160]=[0 | 0 | colsum(W''_0 mol cols)]
// CV1[416]: 0 except [400..407] = colsum(W''_1 mol cols)
struct S1Args {
  const float *Wc[2], *as_c[2], *ad_c[2], *bc[2];
  const float *Wd[2], *as_d[2], *ad_d[2], *bd[2];
  const float *Wm[2], *as_m[2], *ad_m[2], *bm[2];
  const float *Wl[2], *bl[2];
  const float *bp;
  float *WPP[2];
  float *BL[2], *CL[2];
  float *BV_P, *CV_P, *CV1;
};
__global__ __launch_bounds__(256) void k_stage1(S1Args a) {
  const int L = blockIdx.x;
  const int t = threadIdx.x;
  __shared__ float csm[128];
  for (int idx = t; idx < 128 * 24; idx += 256) {
    int k = idx / 24, slot = idx % 24;
    int rel = slot >> 3, inner = slot & 7, h = inner & 3, isD = inner >> 2;
    const float *W, *av;
    int fh, heads;
    if (rel == 0)      { W = a.Wc[L]; av = isD ? a.ad_c[L] : a.as_c[L]; fh = 64; heads = 2; }
    else if (rel == 1) { W = a.Wd[L]; av = isD ? a.ad_d[L] : a.as_d[L]; fh = 64; heads = 2; }
    else               { W = a.Wm[L]; av = isD ? a.ad_m[L] : a.as_m[L]; fh = 32; heads = 4; }
    float s = 0.f;
    if (h < heads)
      for (int f = 0; f < fh; ++f) s += W[k * 128 + h * fh + f] * av[h * fh + f];
    a.WPP[L][idx] = s;
  }
  if (t < 128) {
    float s = 0.f;
    for (int k = 0; k < 128; ++k) s += a.Wm[L][k * 128 + t];
    csm[t] = s;
  }
  __syncthreads();
  if (t < 128) {
    float cs = 0.f, bw = 0.f;
    for (int j = 0; j < 128; ++j) {
      const float wl = a.Wl[L][j * 128 + t];
      cs = fmaf(csm[j], wl, cs);
      bw = fmaf(a.bm[L][j], wl, bw);
    }
    a.CL[L][t] = cs;
    a.BL[L][t] = a.bc[L][t] + a.bd[L][t] + a.bl[L][t] + bw;
  }
  if (L == 0) {
    if (t < 160) {
      float b = 0.f, c = 0.f;
      if (t < 128) b = a.bp[t];
      else if (t < 152) {
        int e = t - 128;
        for (int k = 0; k < 128; ++k) b += a.bp[k] * a.WPP[0][k * 24 + e];
        if (e >= 16) for (int k = 0; k < 128; ++k) c += a.WPP[0][k * 24 + e];
      }
      a.BV_P[t] = b; a.CV_P[t] = c;
    }
  } else {
    for (int t2 = t; t2 < 416; t2 += 256) {
      float c = 0.f;
      if (t2 >= 400 && t2 < 408) {
        const int slot = t2 - 384;   // 16..23 (mol aS+aD)
        for (int k = 0; k < 128; ++k) c += a.WPP[1][k * 24 + slot];
      }
      a.CV1[t2] = c;
    }
  }
}

// ---------------- stage2: EXT_P = Wp @ W''_0  (128x24) ----------------
__global__ __launch_bounds__(256) void k_stage2(const float* __restrict__ Wp,
                                                const float* __restrict__ WPP0,
                                                float* __restrict__ EXT_P) {
  for (int idx = blockIdx.x * 256 + threadIdx.x; idx < 128 * 24; idx += gridDim.x * 256) {
    int k = idx / 24, c = idx % 24;
    float s = 0.f;
    for (int j = 0; j < 128; ++j) s += Wp[k * 128 + j] * WPP0[j * 24 + c];
    EXT_P[idx] = s;
  }
}

// ---------------- pack dense -> MFMA fragment images (hi/lo bf16) ----------------
// idx = (tile*64+lane)*8+j ; tile = nt*nkt+kt ; k = kt*32+(lane>>4)*8+j ; col = nt*16+(lane&15)
// img0: proj [Wp | EXT_P] 10nt,4kt   img1: [W1c|W1d|W1m] 24nt,4kt
// img2: [W2c|W2d|W2m|WPP1|0] 26nt,4kt   img3/4: [I128 ; Wl] 8nt,8kt
struct PackArgs {
  const float *Wp, *EXT_P;
  const float *W1c, *W1d, *W1m;
  const float *W2c, *W2d, *W2m, *WPP1;
  const float *Wl1, *Wl2;
  ushort_t *hi[5], *lo[5];
};
__global__ __launch_bounds__(256) void k_pack(PackArgs p) {
  const int img = blockIdx.y;
  const int nkt = (img >= 3) ? 8 : 4;
  const int nnt = (img == 0) ? 10 : ((img == 1) ? 24 : ((img == 2) ? 26 : 8));
  const int nfrag = nnt * nkt * 512;
  for (int idx = blockIdx.x * 256 + threadIdx.x; idx < nfrag; idx += gridDim.x * 256) {
    int j = idx & 7, lane = (idx >> 3) & 63;
    int kt = (idx >> 9) % nkt, nt = (idx >> 9) / nkt;
    int k = kt * 32 + (lane >> 4) * 8 + j;
    int col = nt * 16 + (lane & 15);
    float w = 0.f;
    if (img == 0) {
      if (col < 128) w = p.Wp[k * 128 + col];
      else if (col < 152) w = p.EXT_P[k * 24 + col - 128];
    } else if (img == 1) {
      if (col < 128)      w = p.W1c[k * 128 + col];
      else if (col < 256) w = p.W1d[k * 128 + col - 128];
      else                w = p.W1m[k * 128 + col - 256];
    } else if (img == 2) {
      if (col < 128)      w = p.W2c[k * 128 + col];
      else if (col < 256) w = p.W2d[k * 128 + col - 128];
      else if (col < 384) w = p.W2m[k * 128 + col - 256];
      else if (col < 408) w = p.WPP1[k * 24 + col - 384];
    } else {
      const float* Wl = (img == 3) ? p.Wl1 : p.Wl2;
      if (k < 128) w = (k == col) ? 1.f : 0.f;
      else         w = Wl[(k - 128) * 128 + col];
    }
    ushort_t h = f2bf(w);
    p.hi[img][idx] = h;
    p.lo[img][idx] = f2bf(w - bf2f(h));
  }
}

// ---------------- proj GEMM: f32 A split-bf16, K=128, C f32 + 24 alpha cols ----------
template <int NNT, int NCMAIN>
__global__ __launch_bounds__(256, 2) void k_gmm(
    const float* __restrict__ A, const ushort_t* __restrict__ HI,
    const ushort_t* __restrict__ LO, const float* __restrict__ biasv,
    const float* __restrict__ csumv, const float* __restrict__ gsum, float gscale,
    float* __restrict__ C, float* __restrict__ ALPHA, int n)
{
  const int wave = threadIdx.x >> 6, lane = threadIdx.x & 63;
  const int m = lane & 15, kq = lane >> 4;
  const float cb = gscale * gsum[0];
  const int rw = blockIdx.x * 128 + wave * 32;

  short8 ah[2][4], al[2][4];
  #pragma unroll
  for (int sub = 0; sub < 2; ++sub) {
    const int row = rw + sub * 16 + m;
    const bool ok = row < n;
    const float* ap = A + (size_t)row * 128 + kq * 8;
    #pragma unroll
    for (int kt = 0; kt < 4; ++kt) {
      f32x4 x0 = {0.f, 0.f, 0.f, 0.f}, x1 = {0.f, 0.f, 0.f, 0.f};
      if (ok) { x0 = *(const f32x4*)(ap + kt * 32); x1 = *(const f32x4*)(ap + kt * 32 + 4); }
      #pragma unroll
      for (int j = 0; j < 4; ++j) {
        ushort_t h0 = f2bf(x0[j]);
        ah[sub][kt][j] = (short)h0;
        al[sub][kt][j] = (short)f2bf(x0[j] - bf2f(h0));
        ushort_t h1 = f2bf(x1[j]);
        ah[sub][kt][4 + j] = (short)h1;
        al[sub][kt][4 + j] = (short)f2bf(x1[j] - bf2f(h1));
      }
    }
  }
  f32x4 acc[2][NNT];
  #pragma unroll
  for (int sub = 0; sub < 2; ++sub)
    #pragma unroll
    for (int nt = 0; nt < NNT; ++nt) acc[sub][nt] = f32x4{0.f, 0.f, 0.f, 0.f};

  #pragma unroll
  for (int nt = 0; nt < NNT; ++nt) {
    #pragma unroll
    for (int kt = 0; kt < 4; ++kt) {
      const int fo = ((nt * 4 + kt) * 64 + lane) * 8;
      const short8 bh = *(const short8*)&HI[fo];
      const short8 bl = *(const short8*)&LO[fo];
      #pragma unroll
      for (int sub = 0; sub < 2; ++sub) {
        acc[sub][nt] = __builtin_amdgcn_mfma_f32_16x16x32_bf16(ah[sub][kt], bh, acc[sub][nt], 0, 0, 0);
        acc[sub][nt] = __builtin_amdgcn_mfma_f32_16x16x32_bf16(al[sub][kt], bh, acc[sub][nt], 0, 0, 0);
        acc[sub][nt] = __builtin_amdgcn_mfma_f32_16x16x32_bf16(ah[sub][kt], bl, acc[sub][nt], 0, 0, 0);
      }
    }
  }
  #pragma unroll
  for (int sub = 0; sub < 2; ++sub) {
    const int rbase = rw + sub * 16 + kq * 4;
    #pragma unroll
    for (int nt = 0; nt < NNT; ++nt) {
      const int col = nt * 16 + m;
      const float add = biasv[col] + cb * csumv[col];
      #pragma unroll
      for (int r = 0; r < 4; ++r) {
        const float v = acc[sub][nt][r] + add;
        const int row = rbase + r;
        if (col < NCMAIN) C[(size_t)row * 128 + col] = v;
        else {
          const int ai = col - NCMAIN;
          if (ai < 24) ALPHA[(size_t)row * 24 + ai] = v;
        }
      }
    }
  }
}

// ---------------- GEMM1: f32 A split-bf16, K=128, bf16 C (HT) + alpha cols ----------
template <int NNT, int NCMAIN>
__global__ __launch_bounds__(256, 2) void k_gmmA16(
    const float* __restrict__ A, const ushort_t* __restrict__ HI,
    const ushort_t* __restrict__ LO,
    const float* __restrict__ csumv, const float* __restrict__ gsum, float gscale,
    ushort_t* __restrict__ C16, float* __restrict__ ALPHA, int n)
{
  const int wave = threadIdx.x >> 6, lane = threadIdx.x & 63;
  const int m = lane & 15, kq = lane >> 4;
  const int rw = blockIdx.x * 64 + wave * 16;
  const int row = rw + m;
  const bool ok = row < n;
  const float* ap = A + (size_t)row * 128 + kq * 8;

  short8 ah[4], al[4];
  #pragma unroll
  for (int kt = 0; kt < 4; ++kt) {
    f32x4 x0 = {0.f, 0.f, 0.f, 0.f}, x1 = {0.f, 0.f, 0.f, 0.f};
    if (ok) { x0 = *(const f32x4*)(ap + kt * 32); x1 = *(const f32x4*)(ap + kt * 32 + 4); }
    #pragma unroll
    for (int j = 0; j < 4; ++j) {
      ushort_t h0 = f2bf(x0[j]);
      ah[kt][j] = (short)h0;
      al[kt][j] = (short)f2bf(x0[j] - bf2f(h0));
      ushort_t h1 = f2bf(x1[j]);
      ah[kt][4 + j] = (short)h1;
      al[kt][4 + j] = (short)f2bf(x1[j] - bf2f(h1));
    }
  }
  f32x4 acc[NNT];
  #pragma unroll
  for (int nt = 0; nt < NNT; ++nt) acc[nt] = f32x4{0.f, 0.f, 0.f, 0.f};

  #pragma unroll
  for (int nt = 0; nt < NNT; ++nt) {
    #pragma unroll
    for (int kt = 0; kt < 4; ++kt) {
      const int fo = ((nt * 4 + kt) * 64 + lane) * 8;
      const short8 bh = *(const short8*)&HI[fo];
      const short8 bl = *(const short8*)&LO[fo];
      acc[nt] = __builtin_amdgcn_mfma_f32_16x16x32_bf16(ah[kt], bh, acc[nt], 0, 0, 0);
      acc[nt] = __builtin_amdgcn_mfma_f32_16x16x32_bf16(al[kt], bh, acc[nt], 0, 0, 0);
      acc[nt] = __builtin_amdgcn_mfma_f32_16x16x32_bf16(ah[kt], bl, acc[nt], 0, 0, 0);
    }
  }
  const float cb = gscale * gsum[0];
  const int rbase = rw + kq * 4;
  #pragma unroll
  for (int nt = 0; nt < NNT; ++nt) {
    const int col = nt * 16 + m;
    const float add = cb * csumv[col];
    #pragma unroll
    for (int r = 0; r < 4; ++r) {
      const float v = acc[nt][r] + add;
      const int row2 = rbase + r;
      if (col < NCMAIN) {
        if (row2 < n) C16[(size_t)row2 * 384 + col] = f2bf(v);
      } else {
        const int ai = col - NCMAIN;
        if (ai < 24) ALPHA[(size_t)row2 * 24 + ai] = v;
      }
    }
  }
}

// ---------------- GEMM2: bf16 A (U, K=256), B=[I;Wl], +bias+cshift+ReLU, f32 C ------
__global__ __launch_bounds__(256, 2) void k_gmm2(
    const ushort_t* __restrict__ U16, const ushort_t* __restrict__ HI,
    const ushort_t* __restrict__ LO, const float* __restrict__ biasv,
    const float* __restrict__ csumv, const float* __restrict__ gsum, float gscale,
    float* __restrict__ C, int n)
{
  const int wave = threadIdx.x >> 6, lane = threadIdx.x & 63;
  const int m = lane & 15, kq = lane >> 4;
  const int rw = blockIdx.x * 256 + wave * 64;

  f32x4 acc[4][8];
  #pragma unroll
  for (int sub = 0; sub < 4; ++sub)
    #pragma unroll
    for (int nt = 0; nt < 8; ++nt) acc[sub][nt] = f32x4{0.f, 0.f, 0.f, 0.f};

  for (int kt = 0; kt < 8; ++kt) {
    short8 ah[4];
    #pragma unroll
    for (int sub = 0; sub < 4; ++sub) {
      const int row = rw + sub * 16 + m;
      short8 z = {0, 0, 0, 0, 0, 0, 0, 0};
      ah[sub] = (row < n) ? *(const short8*)(U16 + (size_t)row * 256 + kt * 32 + kq * 8) : z;
    }
    #pragma unroll
    for (int nt = 0; nt < 8; ++nt) {
      const int fo = ((nt * 8 + kt) * 64 + lane) * 8;
      const short8 bh = *(const short8*)&HI[fo];
      const short8 bl = *(const short8*)&LO[fo];
      #pragma unroll
      for (int sub = 0; sub < 4; ++sub) {
        acc[sub][nt] = __builtin_amdgcn_mfma_f32_16x16x32_bf16(ah[sub], bh, acc[sub][nt], 0, 0, 0);
        acc[sub][nt] = __builtin_amdgcn_mfma_f32_16x16x32_bf16(ah[sub], bl, acc[sub][nt], 0, 0, 0);
      }
    }
  }
  const float cb = gscale * gsum[0];
  #pragma unroll
  for (int sub = 0; sub < 4; ++sub) {
    const int rbase = rw + sub * 16 + kq * 4;
    #pragma unroll
    for (int nt = 0; nt < 8; ++nt) {
      const int col = nt * 16 + m;
      const float add = biasv[col] + cb * csumv[col];
      #pragma unroll
      for (int r = 0; r < 4; ++r)
        C[(size_t)(rbase + r) * 128 + col] = fmaxf(acc[sub][nt][r] + add, 0.f);
    }
  }
}

// ---------------- fused conv: per-head softmax aggregation of HT blocks -------------
// which=0 wave: chem+cond interleaved -> U[:,0:128] = Vc+Vd ; which=1 wave: mol -> U[:,128:256]
__device__ __forceinline__ float2 aggR(
    const ushort_t* __restrict__ HT, const float* __restrict__ ALPHA,
    const int* __restrict__ SRCS, const int* __restrict__ OFF,
    int i, int rel, int base, int shift, int c0, int N_)
{
  const int sb = rel * 8, hd = c0 >> shift;
  const float aSi = ALPHA[(size_t)i * 24 + sb + hd];
  const float aDi = ALPHA[(size_t)i * 24 + sb + 4 + hd];
  const int idx = rel * N_ + i;
  const int e0 = OFF[idx];
  const int deg = OFF[idx + 1] - e0;
  const int* sp = SRCS + e0;

  float mx = lrelu(aSi + aDi), z = 1.f;
  const ushort2 sh = *(const ushort2*)(HT + (size_t)i * 384 + base + c0);
  float a0 = bf2f(sh.x), a1 = bf2f(sh.y);
  for (int j = 0; j < deg; ++j) {
    const int s = sp[j];
    const float e = lrelu(ALPHA[(size_t)s * 24 + sb + hd] + aDi);
    const float mn = fmaxf(mx, e);
    const float f1 = __expf(mx - mn), f2 = __expf(e - mn);
    const ushort2 hv = *(const ushort2*)(HT + (size_t)s * 384 + base + c0);
    z = z * f1 + f2;
    a0 = a0 * f1 + f2 * bf2f(hv.x);
    a1 = a1 * f1 + f2 * bf2f(hv.y);
    mx = mn;
  }
  const float inv = 1.f / (z + 1e-16f);
  return float2{a0 * inv, a1 * inv};
}

__global__ __launch_bounds__(256) void k_fconv(
    const ushort_t* __restrict__ HT, const float* __restrict__ ALPHA,
    const int* __restrict__ SRCS, const int* __restrict__ OFF,
    ushort_t* __restrict__ U16, int N_)
{
  const int wid = blockIdx.x * 4 + (threadIdx.x >> 6);
  if (wid >= 2 * N_) return;
  const int i = wid >> 1;
  const int which = wid & 1;
  const int lane = threadIdx.x & 63;
  const int c0 = lane * 2;
  if (which == 0) {
    // chem (rel0, base 0) + cond (rel1, base 128), interleaved for latency overlap
    const int hd = c0 >> 6;
    const float aS0 = ALPHA[(size_t)i * 24 + hd],     aD0 = ALPHA[(size_t)i * 24 + 4 + hd];
    const float aS1 = ALPHA[(size_t)i * 24 + 8 + hd], aD1 = ALPHA[(size_t)i * 24 + 12 + hd];
    const int ea0 = OFF[i],       da = OFF[i + 1] - ea0;
    const int eb0 = OFF[N_ + i],  db = OFF[N_ + i + 1] - eb0;
    const int* spa = SRCS + ea0;
    const int* spb = SRCS + eb0;
    const ushort2 sa = *(const ushort2*)(HT + (size_t)i * 384 + c0);
    const ushort2 sb2 = *(const ushort2*)(HT + (size_t)i * 384 + 128 + c0);
    float mxa = lrelu(aS0 + aD0), za = 1.f, a0 = bf2f(sa.x), a1 = bf2f(sa.y);
    float mxb = lrelu(aS1 + aD1), zb = 1.f, b0 = bf2f(sb2.x), b1 = bf2f(sb2.y);
    const int dmax = (da > db) ? da : db;
    for (int j = 0; j < dmax; ++j) {
      if (j < da) {
        const int s = spa[j];
        const float e = lrelu(ALPHA[(size_t)s * 24 + hd] + aD0);
        const float mn = fmaxf(mxa, e);
        const float f1 = __expf(mxa - mn), f2 = __expf(e - mn);
        const ushort2 hv = *(const ushort2*)(HT + (size_t)s * 384 + c0);
        za = za * f1 + f2;
        a0 = a0 * f1 + f2 * bf2f(hv.x);
        a1 = a1 * f1 + f2 * bf2f(hv.y);
        mxa = mn;
      }
      if (j < db) {
        const int s = spb[j];
        const float e = lrelu(ALPHA[(size_t)s * 24 + 8 + hd] + aD1);
        const float mn = fmaxf(mxb, e);
        const float f1 = __expf(mxb - mn), f2 = __expf(e - mn);
        const ushort2 hv = *(const ushort2*)(HT + (size_t)s * 384 + 128 + c0);
        zb = zb * f1 + f2;
        b0 = b0 * f1 + f2 * bf2f(hv.x);
        b1 = b1 * f1 + f2 * bf2f(hv.y);
        mxb = mn;
      }
    }
    const float ia = 1.f / (za + 1e-16f), ib = 1.f / (zb + 1e-16f);
    ushort_t* up = U16 + (size_t)i * 256 + c0;
    up[0] = f2bf(a0 * ia + b0 * ib);
    up[1] = f2bf(a1 * ia + b1 * ib);
  } else {
    const float2 vm = aggR(HT, ALPHA, SRCS, OFF, i, 2, 256, 5, c0, N_);
    ushort_t* up = U16 + (size_t)i * 256 + 128 + c0;
    up[0] = f2bf(vm.x);
    up[1] = f2bf(vm.y);
  }
}

// ---------------- output heads ----------------
__global__ __launch_bounds__(256) void k_head(
    const float* __restrict__ h2, const float* __restrict__ Wy, const float* __restrict__ by,
    const float* __restrict__ Wa, const float* __restrict__ ba,
    float* __restrict__ out, int n)
{
  const int r = blockIdx.x * 4 + (threadIdx.x >> 6);
  const int L = threadIdx.x & 63;
  if (r >= n) return;
  const float a = h2[(size_t)r * 128 + L];
  const float b = h2[(size_t)r * 128 + 64 + L];
  float py = a * Wy[L] + b * Wy[64 + L];
  float pa = a * Wa[L] + b * Wa[64 + L];
  #pragma unroll
  for (int o = 32; o; o >>= 1) { py += __shfl_down(py, o); pa += __shfl_down(pa, o); }
  if (L == 0) {
    out[(size_t)r * 2]     = py + by[0];
    out[(size_t)r * 2 + 1] = pa + ba[0];
  }
}

extern "C" void kernel_launch(void* const* d_in, const int* in_sizes, int n_in,
                              void* d_out, int out_size, void* d_ws, size_t ws_size,
                              hipStream_t stream) {
  const int N = in_sizes[0] / 128;
  const int E = in_sizes[2] / 2;
  const int npad = (N + 255) & ~255;
  const int M = 3 * N;

  const float* x       = (const float*)d_in[0];
  const float* pos     = (const float*)d_in[1];
  const int*   ei_chem = (const int*)d_in[2];
  const int*   ei_cond = (const int*)d_in[3];
  const int*   ei_mol  = (const int*)d_in[4];
  const float* Wp = (const float*)d_in[5];
  const float* Wy = (const float*)d_in[35];
  const float* by = (const float*)d_in[36];
  const float* Wa = (const float*)d_in[37];
  const float* ba = (const float*)d_in[38];

  char* ws = (char*)d_ws;
  size_t off = 0;
  auto alloc = [&](size_t bytes) -> void* {
    void* p = ws + off; off += (bytes + 255) & ~(size_t)255; return p;
  };
  float*    H     = (float*)alloc((size_t)npad * 128 * sizeof(float));     // h0/h1/h2
  ushort_t* HT    = (ushort_t*)alloc((size_t)N * 384 * sizeof(ushort_t)); // bf16 h@[Wc|Wd|Wm]
  ushort_t* U     = (ushort_t*)alloc((size_t)N * 256 * sizeof(ushort_t)); // bf16 [Vcd|Vm]
  float*    ALPHA = (float*)alloc((size_t)npad * 24 * sizeof(float));
  int*      OFF   = (int*)alloc((size_t)(M + 64) * sizeof(int));
  int*      WPOS  = (int*)alloc((size_t)M * sizeof(int));
  int*      SRCS  = (int*)alloc((size_t)3 * E * sizeof(int));
  const int nblk = (M + SCHUNK - 1) / SCHUNK;
  int*      BSUM  = (int*)alloc((size_t)nblk * sizeof(int));
  float*    GSUM  = (float*)alloc(256);

  float* WPP0  = (float*)alloc(128 * 24 * sizeof(float));
  float* WPP1  = (float*)alloc(128 * 24 * sizeof(float));
  float* EXT_P = (float*)alloc(128 * 24 * sizeof(float));
  float* BL0  = (float*)alloc(128 * sizeof(float));
  float* CL0  = (float*)alloc(128 * sizeof(float));
  float* BL1  = (float*)alloc(128 * sizeof(float));
  float* CL1  = (float*)alloc(128 * sizeof(float));
  float* BV_P = (float*)alloc(160 * sizeof(float));
  float* CV_P = (float*)alloc(160 * sizeof(float));
  float* CV1  = (float*)alloc(416 * sizeof(float));
  // fragment images: 0=proj 1=G1L1 2=G1L2 3=G2L1 4=G2L2
  const int isz[5] = {20480, 49152, 53248, 32768, 32768};
  ushort_t *HIs[5], *LOs[5];
  for (int s = 0; s < 5; ++s) {
    HIs[s] = (ushort_t*)alloc((size_t)isz[s] * 2);
    LOs[s] = (ushort_t*)alloc((size_t)isz[s] * 2);
  }

  hipMemsetAsync(OFF, 0, (size_t)(M + 1) * sizeof(int), stream);
  hipMemsetAsync(GSUM, 0, sizeof(float), stream);

  const int egrid = (E + 255) / 256;
  dim3 eg3(egrid, 3);
  k_count<<<eg3, 256, 0, stream>>>(ei_chem, ei_cond, ei_mol, OFF, E, N);
  k_geo<<<egrid, 256, 0, stream>>>(pos, ei_mol, GSUM, E);
  k_scanA<<<nblk, 256, 0, stream>>>(OFF, BSUM, M);
  k_scanB<<<1, 512, 0, stream>>>(BSUM, nblk, OFF, M);
  k_scanC<<<nblk, 256, 0, stream>>>(OFF, BSUM, WPOS, M);
  k_fill<<<eg3, 256, 0, stream>>>(ei_chem, ei_cond, ei_mol, WPOS, SRCS, E, N);

  S1Args s1{};
  for (int L = 0; L < 2; ++L) {
    const int b = (L == 0) ? 7 : 21;
    s1.Wc[L] = (const float*)d_in[b+0];  s1.as_c[L] = (const float*)d_in[b+1];
    s1.ad_c[L] = (const float*)d_in[b+2]; s1.bc[L] = (const float*)d_in[b+3];
    s1.Wd[L] = (const float*)d_in[b+4];  s1.as_d[L] = (const float*)d_in[b+5];
    s1.ad_d[L] = (const float*)d_in[b+6]; s1.bd[L] = (const float*)d_in[b+7];
    s1.Wm[L] = (const float*)d_in[b+8];  s1.as_m[L] = (const float*)d_in[b+9];
    s1.ad_m[L] = (const float*)d_in[b+10]; s1.bm[L] = (const float*)d_in[b+11];
    s1.Wl[L] = (const float*)d_in[b+12]; s1.bl[L] = (const float*)d_in[b+13];
  }
  s1.bp = (const float*)d_in[6];
  s1.WPP[0] = WPP0; s1.WPP[1] = WPP1;
  s1.BL[0] = BL0; s1.CL[0] = CL0; s1.BL[1] = BL1; s1.CL[1] = CL1;
  s1.BV_P = BV_P; s1.CV_P = CV_P; s1.CV1 = CV1;
  k_stage1<<<2, 256, 0, stream>>>(s1);
  k_stage2<<<12, 256, 0, stream>>>(Wp, WPP0, EXT_P);

  PackArgs pk{};
  pk.Wp = Wp; pk.EXT_P = EXT_P;
  pk.W1c = s1.Wc[0]; pk.W1d = s1.Wd[0]; pk.W1m = s1.Wm[0];
  pk.W2c = s1.Wc[1]; pk.W2d = s1.Wd[1]; pk.W2m = s1.Wm[1]; pk.WPP1 = WPP1;
  pk.Wl1 = s1.Wl[0]; pk.Wl2 = s1.Wl[1];
  for (int s = 0; s < 5; ++s) { pk.hi[s] = HIs[s]; pk.lo[s] = LOs[s]; }
  dim3 pg(32, 5);
  k_pack<<<pg, 256, 0, stream>>>(pk);

  const float gscale = 0.1f / (float)E;
  const int g128  = npad / 128;
  const int g64   = (N + 63) / 64;
  const int g256  = npad / 256;
  const int gconv = (2 * N + 3) / 4;

  // h0 (+ layer-1 alphas) = x @ [Wp | Wp@W1''] + folds
  k_gmm<10, 128><<<g128, 256, 0, stream>>>(x, HIs[0], LOs[0], BV_P, CV_P, GSUM, gscale,
                                           H, ALPHA, N);
  // layer 1: HT = h0@[W1c|W1d|W1m] ; conv ; h1 = relu(Vcd + Vm@Wl1 + BL0 + c*CL0)
  k_gmmA16<24, 384><<<g64, 256, 0, stream>>>(H, HIs[1], LOs[1], CV1, GSUM, 0.f,
                                             HT, ALPHA, N);
  k_fconv<<<gconv, 256, 0, stream>>>(HT, ALPHA, SRCS, OFF, U, N);
  k_gmm2<<<g256, 256, 0, stream>>>(U, HIs[3], LOs[3], BL0, CL0, GSUM, gscale, H, N);
  // layer 2: HT = h1@[W2c|W2d|W2m] + layer-2 alphas (incl. mol cshift via CV1)
  k_gmmA16<26, 384><<<g64, 256, 0, stream>>>(H, HIs[2], LOs[2], CV1, GSUM, gscale,
                                             HT, ALPHA, N);
  k_fconv<<<gconv, 256, 0, stream>>>(HT, ALPHA, SRCS, OFF, U, N);
  k_gmm2<<<g256, 256, 0, stream>>>(U, HIs[4], LOs[4], BL1, CL1, GSUM, gscale, H, N);

  k_head<<<(N + 3) / 4, 256, 0, stream>>>(H, Wy, by, Wa, ba, (float*)d_out, N);
}

// Round 7
// 1105.593 us; speedup vs baseline: 1.3027x; 1.0434x over previous
//
#include <hip/hip_runtime.h>
#include <math.h>

typedef short short8 __attribute__((ext_vector_type(8)));
typedef float f32x4 __attribute__((ext_vector_type(4)));
typedef unsigned short ushort_t;

#define SCHUNK 1024

__device__ __forceinline__ ushort_t f2bf(float f) {  // RNE f32->bf16
  unsigned u = __float_as_uint(f);
  u += 0x7FFF + ((u >> 16) & 1);
  return (ushort_t)(u >> 16);
}
__device__ __forceinline__ float bf2f(ushort_t s) { return __uint_as_float(((unsigned)s) << 16); }
__device__ __forceinline__ float lrelu(float v) { return v > 0.f ? v : 0.2f * v; }

// ---------------- degree count (3 relations via blockIdx.y) ----------------
__global__ void k_count(const int* __restrict__ ei0, const int* __restrict__ ei1,
                        const int* __restrict__ ei2, int* __restrict__ cnt, int E, int N_) {
  int e = blockIdx.x * 256 + threadIdx.x;
  if (e >= E) return;
  const int r = blockIdx.y;
  const int* ei = (r == 0) ? ei0 : (r == 1) ? ei1 : ei2;
  atomicAdd(&cnt[r * N_ + ei[E + e]], 1);
}

// ---------------- two-level exclusive scan of cnt[0..M) ----------------
__global__ __launch_bounds__(256) void k_scanA(const int* __restrict__ cnt,
                                               int* __restrict__ bsum, int M) {
  __shared__ int sh[256];
  const int t = threadIdx.x;
  const int base = blockIdx.x * SCHUNK + t * 4;
  int s = 0;
  #pragma unroll
  for (int j = 0; j < 4; ++j) { int id = base + j; if (id < M) s += cnt[id]; }
  sh[t] = s;
  __syncthreads();
  for (int o = 128; o; o >>= 1) { if (t < o) sh[t] += sh[t + o]; __syncthreads(); }
  if (t == 0) bsum[blockIdx.x] = sh[0];
}

__global__ __launch_bounds__(512) void k_scanB(int* __restrict__ bsum, int nblk,
                                               int* __restrict__ off, int M) {
  __shared__ int sh[512];
  const int t = threadIdx.x;
  const int v = (t < nblk) ? bsum[t] : 0;
  sh[t] = v;
  __syncthreads();
  for (int o = 1; o < 512; o <<= 1) {
    int xv = (t >= o) ? sh[t - o] : 0;
    __syncthreads();
    sh[t] += xv;
    __syncthreads();
  }
  if (t < nblk) bsum[t] = sh[t] - v;   // exclusive
  if (t == 511) off[M] = sh[511];
}

__global__ __launch_bounds__(256) void k_scanC(int* __restrict__ cntoff,
                                               const int* __restrict__ boff,
                                               int* __restrict__ wpos, int M) {
  __shared__ int sh[256];
  const int t = threadIdx.x;
  const int base = blockIdx.x * SCHUNK + t * 4;
  int v[4]; int s = 0;
  #pragma unroll
  for (int j = 0; j < 4; ++j) { int id = base + j; v[j] = (id < M) ? cntoff[id] : 0; s += v[j]; }
  sh[t] = s;
  __syncthreads();
  for (int o = 1; o < 256; o <<= 1) {
    int xv = (t >= o) ? sh[t - o] : 0;
    __syncthreads();
    sh[t] += xv;
    __syncthreads();
  }
  int excl = boff[blockIdx.x] + sh[t] - s;
  #pragma unroll
  for (int j = 0; j < 4; ++j) {
    int id = base + j;
    if (id < M) { cntoff[id] = excl; wpos[id] = excl; excl += v[j]; }
  }
}

// ---------------- CSR fill ----------------
__global__ void k_fill(const int* __restrict__ ei0, const int* __restrict__ ei1,
                       const int* __restrict__ ei2, int* __restrict__ wpos,
                       int* __restrict__ srcs, int E, int N_) {
  int e = blockIdx.x * 256 + threadIdx.x;
  if (e >= E) return;
  const int r = blockIdx.y;
  const int* ei = (r == 0) ? ei0 : (r == 1) ? ei1 : ei2;
  const int src = ei[e], dst = ei[E + e];
  const int p = atomicAdd(&wpos[r * N_ + dst], 1);
  srcs[p] = src;
}

// ---------------- geo distance sum over ei_mol ----------------
__global__ void k_geo(const float* __restrict__ pos, const int* __restrict__ ei,
                      float* gsum, int E) {
  int e = blockIdx.x * 256 + threadIdx.x;
  float d = 0.f;
  if (e < E) {
    int r = ei[e], c = ei[E + e];
    float dx = pos[3*r]   - pos[3*c];
    float dy = pos[3*r+1] - pos[3*c+1];
    float dz = pos[3*r+2] - pos[3*c+2];
    d = sqrtf(dx*dx + dy*dy + dz*dz);
  }
  #pragma unroll
  for (int o = 32; o; o >>= 1) d += __shfl_down(d, o);
  if ((threadIdx.x & 63) == 0) atomicAdd(gsum, d);
}

// ---------------- stage1: dense weight products + bias/csum vectors ----------------
struct S1Args {
  const float *Wc[2], *as_c[2], *ad_c[2], *bc[2];
  const float *Wd[2], *as_d[2], *ad_d[2], *bd[2];
  const float *Wm[2], *as_m[2], *ad_m[2], *bm[2];
  const float *Wl[2], *bl[2];
  const float *bp;
  float *WPP[2];
  float *BL[2], *CL[2];
  float *BV_P, *CV_P, *CV1;
};
__global__ __launch_bounds__(256) void k_stage1(S1Args a) {
  const int L = blockIdx.x;
  const int t = threadIdx.x;
  __shared__ float csm[128];
  for (int idx = t; idx < 128 * 24; idx += 256) {
    int k = idx / 24, slot = idx % 24;
    int rel = slot >> 3, inner = slot & 7, h = inner & 3, isD = inner >> 2;
    const float *W, *av;
    int fh, heads;
    if (rel == 0)      { W = a.Wc[L]; av = isD ? a.ad_c[L] : a.as_c[L]; fh = 64; heads = 2; }
    else if (rel == 1) { W = a.Wd[L]; av = isD ? a.ad_d[L] : a.as_d[L]; fh = 64; heads = 2; }
    else               { W = a.Wm[L]; av = isD ? a.ad_m[L] : a.as_m[L]; fh = 32; heads = 4; }
    float s = 0.f;
    if (h < heads)
      for (int f = 0; f < fh; ++f) s += W[k * 128 + h * fh + f] * av[h * fh + f];
    a.WPP[L][idx] = s;
  }
  if (t < 128) {
    float s = 0.f;
    for (int k = 0; k < 128; ++k) s += a.Wm[L][k * 128 + t];
    csm[t] = s;
  }
  __syncthreads();
  if (t < 128) {
    float cs = 0.f, bw = 0.f;
    for (int j = 0; j < 128; ++j) {
      const float wl = a.Wl[L][j * 128 + t];
      cs = fmaf(csm[j], wl, cs);
      bw = fmaf(a.bm[L][j], wl, bw);
    }
    a.CL[L][t] = cs;
    a.BL[L][t] = a.bc[L][t] + a.bd[L][t] + a.bl[L][t] + bw;
  }
  if (L == 0) {
    if (t < 160) {
      float b = 0.f, c = 0.f;
      if (t < 128) b = a.bp[t];
      else if (t < 152) {
        int e = t - 128;
        for (int k = 0; k < 128; ++k) b += a.bp[k] * a.WPP[0][k * 24 + e];
        if (e >= 16) for (int k = 0; k < 128; ++k) c += a.WPP[0][k * 24 + e];
      }
      a.BV_P[t] = b; a.CV_P[t] = c;
    }
  } else {
    for (int t2 = t; t2 < 416; t2 += 256) {
      float c = 0.f;
      if (t2 >= 400 && t2 < 408) {
        const int slot = t2 - 384;   // 16..23 (mol aS+aD)
        for (int k = 0; k < 128; ++k) c += a.WPP[1][k * 24 + slot];
      }
      a.CV1[t2] = c;
    }
  }
}

// ---------------- stage2: EXT_P = Wp @ W''_0  (128x24) ----------------
__global__ __launch_bounds__(256) void k_stage2(const float* __restrict__ Wp,
                                                const float* __restrict__ WPP0,
                                                float* __restrict__ EXT_P) {
  for (int idx = blockIdx.x * 256 + threadIdx.x; idx < 128 * 24; idx += gridDim.x * 256) {
    int k = idx / 24, c = idx % 24;
    float s = 0.f;
    for (int j = 0; j < 128; ++j) s += Wp[k * 128 + j] * WPP0[j * 24 + c];
    EXT_P[idx] = s;
  }
}

// ---------------- pack dense -> MFMA fragment images (hi/lo bf16) ----------------
struct PackArgs {
  const float *Wp, *EXT_P;
  const float *W1c, *W1d, *W1m;
  const float *W2c, *W2d, *W2m, *WPP1;
  const float *Wl1, *Wl2;
  ushort_t *hi[5], *lo[5];
};
__global__ __launch_bounds__(256) void k_pack(PackArgs p) {
  const int img = blockIdx.y;
  const int nkt = (img >= 3) ? 8 : 4;
  const int nnt = (img == 0) ? 10 : ((img == 1) ? 24 : ((img == 2) ? 26 : 8));
  const int nfrag = nnt * nkt * 512;
  for (int idx = blockIdx.x * 256 + threadIdx.x; idx < nfrag; idx += gridDim.x * 256) {
    int j = idx & 7, lane = (idx >> 3) & 63;
    int kt = (idx >> 9) % nkt, nt = (idx >> 9) / nkt;
    int k = kt * 32 + (lane >> 4) * 8 + j;
    int col = nt * 16 + (lane & 15);
    float w = 0.f;
    if (img == 0) {
      if (col < 128) w = p.Wp[k * 128 + col];
      else if (col < 152) w = p.EXT_P[k * 24 + col - 128];
    } else if (img == 1) {
      if (col < 128)      w = p.W1c[k * 128 + col];
      else if (col < 256) w = p.W1d[k * 128 + col - 128];
      else                w = p.W1m[k * 128 + col - 256];
    } else if (img == 2) {
      if (col < 128)      w = p.W2c[k * 128 + col];
      else if (col < 256) w = p.W2d[k * 128 + col - 128];
      else if (col < 384) w = p.W2m[k * 128 + col - 256];
      else if (col < 408) w = p.WPP1[k * 24 + col - 384];
    } else {
      const float* Wl = (img == 3) ? p.Wl1 : p.Wl2;
      if (k < 128) w = (k == col) ? 1.f : 0.f;
      else         w = Wl[(k - 128) * 128 + col];
    }
    ushort_t h = f2bf(w);
    p.hi[img][idx] = h;
    p.lo[img][idx] = f2bf(w - bf2f(h));
  }
}

// ---------------- proj GEMM: f32 A -> split-bf16, K=128, out = split-bf16 H + ALPHA --
// 64 rows/wave, col-split via blockIdx.y (CNT nt-tiles per group)
template <int CNT>
__global__ __launch_bounds__(256, 2) void k_proj(
    const float* __restrict__ A, const ushort_t* __restrict__ HI,
    const ushort_t* __restrict__ LO, const float* __restrict__ biasv,
    const float* __restrict__ csumv, const float* __restrict__ gsum, float gscale,
    int ntot, int ncmain,
    ushort_t* __restrict__ Chi, ushort_t* __restrict__ Clo,
    float* __restrict__ ALPHA, int n)
{
  const int wave = threadIdx.x >> 6, lane = threadIdx.x & 63;
  const int m = lane & 15, kq = lane >> 4;
  const int rw = blockIdx.x * 256 + wave * 64;
  const int nt0 = blockIdx.y * CNT;
  const int cnt = (ntot - nt0 < CNT) ? (ntot - nt0) : CNT;

  f32x4 acc[4][CNT];
  #pragma unroll
  for (int sub = 0; sub < 4; ++sub)
    #pragma unroll
    for (int nt = 0; nt < CNT; ++nt) acc[sub][nt] = f32x4{0.f, 0.f, 0.f, 0.f};

  for (int kt = 0; kt < 4; ++kt) {
    short8 ah[4], al[4];
    #pragma unroll
    for (int sub = 0; sub < 4; ++sub) {
      const int row = rw + sub * 16 + m;
      f32x4 x0 = {0.f, 0.f, 0.f, 0.f}, x1 = {0.f, 0.f, 0.f, 0.f};
      if (row < n) {
        const float* ap = A + (size_t)row * 128 + kt * 32 + kq * 8;
        x0 = *(const f32x4*)ap; x1 = *(const f32x4*)(ap + 4);
      }
      #pragma unroll
      for (int j = 0; j < 4; ++j) {
        ushort_t h0 = f2bf(x0[j]);
        ah[sub][j] = (short)h0;
        al[sub][j] = (short)f2bf(x0[j] - bf2f(h0));
        ushort_t h1 = f2bf(x1[j]);
        ah[sub][4 + j] = (short)h1;
        al[sub][4 + j] = (short)f2bf(x1[j] - bf2f(h1));
      }
    }
    #pragma unroll
    for (int nt = 0; nt < CNT; ++nt) {
      if (nt < cnt) {
        const int fo = (((nt0 + nt) * 4 + kt) * 64 + lane) * 8;
        const short8 bh = *(const short8*)&HI[fo];
        const short8 bl = *(const short8*)&LO[fo];
        #pragma unroll
        for (int sub = 0; sub < 4; ++sub) {
          acc[sub][nt] = __builtin_amdgcn_mfma_f32_16x16x32_bf16(ah[sub], bh, acc[sub][nt], 0, 0, 0);
          acc[sub][nt] = __builtin_amdgcn_mfma_f32_16x16x32_bf16(al[sub], bh, acc[sub][nt], 0, 0, 0);
          acc[sub][nt] = __builtin_amdgcn_mfma_f32_16x16x32_bf16(ah[sub], bl, acc[sub][nt], 0, 0, 0);
        }
      }
    }
  }
  const float cb = gscale * gsum[0];
  #pragma unroll
  for (int sub = 0; sub < 4; ++sub) {
    const int rbase = rw + sub * 16 + kq * 4;
    #pragma unroll
    for (int nt = 0; nt < CNT; ++nt) {
      if (nt < cnt) {
        const int col = (nt0 + nt) * 16 + m;
        const float add = biasv[col] + cb * csumv[col];
        #pragma unroll
        for (int r = 0; r < 4; ++r) {
          const float v = acc[sub][nt][r] + add;
          const int row2 = rbase + r;
          if (col < ncmain) {
            if (row2 < n) {
              const ushort_t h = f2bf(v);
              Chi[(size_t)row2 * 128 + col] = h;
              Clo[(size_t)row2 * 128 + col] = f2bf(v - bf2f(h));
            }
          } else {
            const int ai = col - ncmain;
            if (ai < 24) ALPHA[(size_t)row2 * 24 + ai] = v;
          }
        }
      }
    }
  }
}

// ---------------- GEMM1: split-bf16 A (Hhi/Hlo), K=128, bf16 HT + ALPHA cols --------
// 64 rows/wave, col-split via blockIdx.y
template <int CNT>
__global__ __launch_bounds__(256, 2) void k_gemm1(
    const ushort_t* __restrict__ Ahi, const ushort_t* __restrict__ Alo,
    const ushort_t* __restrict__ HI, const ushort_t* __restrict__ LO,
    const float* __restrict__ csumv, const float* __restrict__ gsum, float gscale,
    int ntot, int gsz, int ncmain,
    ushort_t* __restrict__ C16, float* __restrict__ ALPHA, int n)
{
  const int wave = threadIdx.x >> 6, lane = threadIdx.x & 63;
  const int m = lane & 15, kq = lane >> 4;
  const int rw = blockIdx.x * 256 + wave * 64;
  const int nt0 = blockIdx.y * gsz;
  const int cnt0 = ntot - nt0;
  const int cnt = (cnt0 < gsz) ? cnt0 : gsz;

  f32x4 acc[4][CNT];
  #pragma unroll
  for (int sub = 0; sub < 4; ++sub)
    #pragma unroll
    for (int nt = 0; nt < CNT; ++nt) acc[sub][nt] = f32x4{0.f, 0.f, 0.f, 0.f};

  for (int kt = 0; kt < 4; ++kt) {
    short8 ah[4], al[4];
    const short8 z = {0, 0, 0, 0, 0, 0, 0, 0};
    #pragma unroll
    for (int sub = 0; sub < 4; ++sub) {
      const int row = rw + sub * 16 + m;
      const size_t ao = (size_t)row * 128 + kt * 32 + kq * 8;
      ah[sub] = (row < n) ? *(const short8*)(Ahi + ao) : z;
      al[sub] = (row < n) ? *(const short8*)(Alo + ao) : z;
    }
    #pragma unroll
    for (int nt = 0; nt < CNT; ++nt) {
      if (nt < cnt) {
        const int fo = (((nt0 + nt) * 4 + kt) * 64 + lane) * 8;
        const short8 bh = *(const short8*)&HI[fo];
        const short8 bl = *(const short8*)&LO[fo];
        #pragma unroll
        for (int sub = 0; sub < 4; ++sub) {
          acc[sub][nt] = __builtin_amdgcn_mfma_f32_16x16x32_bf16(ah[sub], bh, acc[sub][nt], 0, 0, 0);
          acc[sub][nt] = __builtin_amdgcn_mfma_f32_16x16x32_bf16(al[sub], bh, acc[sub][nt], 0, 0, 0);
          acc[sub][nt] = __builtin_amdgcn_mfma_f32_16x16x32_bf16(ah[sub], bl, acc[sub][nt], 0, 0, 0);
        }
      }
    }
  }
  const float cb = gscale * gsum[0];
  #pragma unroll
  for (int sub = 0; sub < 4; ++sub) {
    const int rbase = rw + sub * 16 + kq * 4;
    #pragma unroll
    for (int nt = 0; nt < CNT; ++nt) {
      if (nt < cnt) {
        const int col = (nt0 + nt) * 16 + m;
        const float add = cb * csumv[col];
        #pragma unroll
        for (int r = 0; r < 4; ++r) {
          const float v = acc[sub][nt][r] + add;
          const int row2 = rbase + r;
          if (col < ncmain) {
            if (row2 < n) C16[(size_t)row2 * 384 + col] = f2bf(v);
          } else {
            const int ai = col - ncmain;
            if (ai < 24) ALPHA[(size_t)row2 * 24 + ai] = v;
          }
        }
      }
    }
  }
}

// ---------------- GEMM2: bf16 A (U, K=256), B=[I;Wl], out split-bf16 H, +ReLU -------
__global__ __launch_bounds__(256, 2) void k_gmm2(
    const ushort_t* __restrict__ U16, const ushort_t* __restrict__ HI,
    const ushort_t* __restrict__ LO, const float* __restrict__ biasv,
    const float* __restrict__ csumv, const float* __restrict__ gsum, float gscale,
    ushort_t* __restrict__ Chi, ushort_t* __restrict__ Clo, int n)
{
  const int wave = threadIdx.x >> 6, lane = threadIdx.x & 63;
  const int m = lane & 15, kq = lane >> 4;
  const int rw = blockIdx.x * 256 + wave * 64;

  f32x4 acc[4][8];
  #pragma unroll
  for (int sub = 0; sub < 4; ++sub)
    #pragma unroll
    for (int nt = 0; nt < 8; ++nt) acc[sub][nt] = f32x4{0.f, 0.f, 0.f, 0.f};

  for (int kt = 0; kt < 8; ++kt) {
    short8 ah[4];
    #pragma unroll
    for (int sub = 0; sub < 4; ++sub) {
      const int row = rw + sub * 16 + m;
      short8 z = {0, 0, 0, 0, 0, 0, 0, 0};
      ah[sub] = (row < n) ? *(const short8*)(U16 + (size_t)row * 256 + kt * 32 + kq * 8) : z;
    }
    #pragma unroll
    for (int nt = 0; nt < 8; ++nt) {
      const int fo = ((nt * 8 + kt) * 64 + lane) * 8;
      const short8 bh = *(const short8*)&HI[fo];
      const short8 bl = *(const short8*)&LO[fo];
      #pragma unroll
      for (int sub = 0; sub < 4; ++sub) {
        acc[sub][nt] = __builtin_amdgcn_mfma_f32_16x16x32_bf16(ah[sub], bh, acc[sub][nt], 0, 0, 0);
        acc[sub][nt] = __builtin_amdgcn_mfma_f32_16x16x32_bf16(ah[sub], bl, acc[sub][nt], 0, 0, 0);
      }
    }
  }
  const float cb = gscale * gsum[0];
  #pragma unroll
  for (int sub = 0; sub < 4; ++sub) {
    const int rbase = rw + sub * 16 + kq * 4;
    #pragma unroll
    for (int nt = 0; nt < 8; ++nt) {
      const int col = nt * 16 + m;
      const float add = biasv[col] + cb * csumv[col];
      #pragma unroll
      for (int r = 0; r < 4; ++r) {
        const int row2 = rbase + r;
        if (row2 < n) {
          const float v = fmaxf(acc[sub][nt][r] + add, 0.f);
          const ushort_t h = f2bf(v);
          Chi[(size_t)row2 * 128 + col] = h;
          Clo[(size_t)row2 * 128 + col] = f2bf(v - bf2f(h));
        }
      }
    }
  }
}

// ---------------- fused conv: per-head softmax aggregation of HT blocks -------------
__device__ __forceinline__ float2 aggR(
    const ushort_t* __restrict__ HT, const float* __restrict__ ALPHA,
    const int* __restrict__ SRCS, const int* __restrict__ OFF,
    int i, int rel, int base, int shift, int c0, int N_)
{
  const int sb = rel * 8, hd = c0 >> shift;
  const float aSi = ALPHA[(size_t)i * 24 + sb + hd];
  const float aDi = ALPHA[(size_t)i * 24 + sb + 4 + hd];
  const int idx = rel * N_ + i;
  const int e0 = OFF[idx];
  const int deg = OFF[idx + 1] - e0;
  const int* sp = SRCS + e0;

  float mx = lrelu(aSi + aDi), z = 1.f;
  const ushort2 sh = *(const ushort2*)(HT + (size_t)i * 384 + base + c0);
  float a0 = bf2f(sh.x), a1 = bf2f(sh.y);
  for (int j = 0; j < deg; ++j) {
    const int s = sp[j];
    const float e = lrelu(ALPHA[(size_t)s * 24 + sb + hd] + aDi);
    const float mn = fmaxf(mx, e);
    const float f1 = __expf(mx - mn), f2 = __expf(e - mn);
    const ushort2 hv = *(const ushort2*)(HT + (size_t)s * 384 + base + c0);
    z = z * f1 + f2;
    a0 = a0 * f1 + f2 * bf2f(hv.x);
    a1 = a1 * f1 + f2 * bf2f(hv.y);
    mx = mn;
  }
  const float inv = 1.f / (z + 1e-16f);
  return float2{a0 * inv, a1 * inv};
}

__global__ __launch_bounds__(256) void k_fconv(
    const ushort_t* __restrict__ HT, const float* __restrict__ ALPHA,
    const int* __restrict__ SRCS, const int* __restrict__ OFF,
    ushort_t* __restrict__ U16, int N_)
{
  const int wid = blockIdx.x * 4 + (threadIdx.x >> 6);
  if (wid >= 2 * N_) return;
  const int i = wid >> 1;
  const int which = wid & 1;
  const int lane = threadIdx.x & 63;
  const int c0 = lane * 2;
  if (which == 0) {
    const int hd = c0 >> 6;
    const float aS0 = ALPHA[(size_t)i * 24 + hd],     aD0 = ALPHA[(size_t)i * 24 + 4 + hd];
    const float aS1 = ALPHA[(size_t)i * 24 + 8 + hd], aD1 = ALPHA[(size_t)i * 24 + 12 + hd];
    const int ea0 = OFF[i],       da = OFF[i + 1] - ea0;
    const int eb0 = OFF[N_ + i],  db = OFF[N_ + i + 1] - eb0;
    const int* spa = SRCS + ea0;
    const int* spb = SRCS + eb0;
    const ushort2 sa = *(const ushort2*)(HT + (size_t)i * 384 + c0);
    const ushort2 sb2 = *(const ushort2*)(HT + (size_t)i * 384 + 128 + c0);
    float mxa = lrelu(aS0 + aD0), za = 1.f, a0 = bf2f(sa.x), a1 = bf2f(sa.y);
    float mxb = lrelu(aS1 + aD1), zb = 1.f, b0 = bf2f(sb2.x), b1 = bf2f(sb2.y);
    const int dmax = (da > db) ? da : db;
    for (int j = 0; j < dmax; ++j) {
      if (j < da) {
        const int s = spa[j];
        const float e = lrelu(ALPHA[(size_t)s * 24 + hd] + aD0);
        const float mn = fmaxf(mxa, e);
        const float f1 = __expf(mxa - mn), f2 = __expf(e - mn);
        const ushort2 hv = *(const ushort2*)(HT + (size_t)s * 384 + c0);
        za = za * f1 + f2;
        a0 = a0 * f1 + f2 * bf2f(hv.x);
        a1 = a1 * f1 + f2 * bf2f(hv.y);
        mxa = mn;
      }
      if (j < db) {
        const int s = spb[j];
        const float e = lrelu(ALPHA[(size_t)s * 24 + 8 + hd] + aD1);
        const float mn = fmaxf(mxb, e);
        const float f1 = __expf(mxb - mn), f2 = __expf(e - mn);
        const ushort2 hv = *(const ushort2*)(HT + (size_t)s * 384 + 128 + c0);
        zb = zb * f1 + f2;
        b0 = b0 * f1 + f2 * bf2f(hv.x);
        b1 = b1 * f1 + f2 * bf2f(hv.y);
        mxb = mn;
      }
    }
    const float ia = 1.f / (za + 1e-16f), ib = 1.f / (zb + 1e-16f);
    ushort_t* up = U16 + (size_t)i * 256 + c0;
    up[0] = f2bf(a0 * ia + b0 * ib);
    up[1] = f2bf(a1 * ia + b1 * ib);
  } else {
    const float2 vm = aggR(HT, ALPHA, SRCS, OFF, i, 2, 256, 5, c0, N_);
    ushort_t* up = U16 + (size_t)i * 256 + 128 + c0;
    up[0] = f2bf(vm.x);
    up[1] = f2bf(vm.y);
  }
}

// ---------------- output heads (split-bf16 H input) ----------------
__global__ __launch_bounds__(256) void k_head(
    const ushort_t* __restrict__ Hhi, const ushort_t* __restrict__ Hlo,
    const float* __restrict__ Wy, const float* __restrict__ by,
    const float* __restrict__ Wa, const float* __restrict__ ba,
    float* __restrict__ out, int n)
{
  const int r = blockIdx.x * 4 + (threadIdx.x >> 6);
  const int L = threadIdx.x & 63;
  if (r >= n) return;
  const float a = bf2f(Hhi[(size_t)r * 128 + L]) + bf2f(Hlo[(size_t)r * 128 + L]);
  const float b = bf2f(Hhi[(size_t)r * 128 + 64 + L]) + bf2f(Hlo[(size_t)r * 128 + 64 + L]);
  float py = a * Wy[L] + b * Wy[64 + L];
  float pa = a * Wa[L] + b * Wa[64 + L];
  #pragma unroll
  for (int o = 32; o; o >>= 1) { py += __shfl_down(py, o); pa += __shfl_down(pa, o); }
  if (L == 0) {
    out[(size_t)r * 2]     = py + by[0];
    out[(size_t)r * 2 + 1] = pa + ba[0];
  }
}

extern "C" void kernel_launch(void* const* d_in, const int* in_sizes, int n_in,
                              void* d_out, int out_size, void* d_ws, size_t ws_size,
                              hipStream_t stream) {
  const int N = in_sizes[0] / 128;
  const int E = in_sizes[2] / 2;
  const int npad = (N + 255) & ~255;
  const int M = 3 * N;

  const float* x       = (const float*)d_in[0];
  const float* pos     = (const float*)d_in[1];
  const int*   ei_chem = (const int*)d_in[2];
  const int*   ei_cond = (const int*)d_in[3];
  const int*   ei_mol  = (const int*)d_in[4];
  const float* Wp = (const float*)d_in[5];
  const float* Wy = (const float*)d_in[35];
  const float* by = (const float*)d_in[36];
  const float* Wa = (const float*)d_in[37];
  const float* ba = (const float*)d_in[38];

  char* ws = (char*)d_ws;
  size_t off = 0;
  auto alloc = [&](size_t bytes) -> void* {
    void* p = ws + off; off += (bytes + 255) & ~(size_t)255; return p;
  };
  ushort_t* Hhi   = (ushort_t*)alloc((size_t)npad * 128 * sizeof(ushort_t)); // h split hi
  ushort_t* Hlo   = (ushort_t*)alloc((size_t)npad * 128 * sizeof(ushort_t)); // h split lo
  ushort_t* HT    = (ushort_t*)alloc((size_t)N * 384 * sizeof(ushort_t));    // bf16 h@[Wc|Wd|Wm]
  ushort_t* U     = (ushort_t*)alloc((size_t)N * 256 * sizeof(ushort_t));    // bf16 [Vcd|Vm]
  float*    ALPHA = (float*)alloc((size_t)npad * 24 * sizeof(float));
  int*      OFF   = (int*)alloc((size_t)(M + 64) * sizeof(int));
  int*      WPOS  = (int*)alloc((size_t)M * sizeof(int));
  int*      SRCS  = (int*)alloc((size_t)3 * E * sizeof(int));
  const int nblk = (M + SCHUNK - 1) / SCHUNK;
  int*      BSUM  = (int*)alloc((size_t)nblk * sizeof(int));
  float*    GSUM  = (float*)alloc(256);

  float* WPP0  = (float*)alloc(128 * 24 * sizeof(float));
  float* WPP1  = (float*)alloc(128 * 24 * sizeof(float));
  float* EXT_P = (float*)alloc(128 * 24 * sizeof(float));
  float* BL0  = (float*)alloc(128 * sizeof(float));
  float* CL0  = (float*)alloc(128 * sizeof(float));
  float* BL1  = (float*)alloc(128 * sizeof(float));
  float* CL1  = (float*)alloc(128 * sizeof(float));
  float* BV_P = (float*)alloc(160 * sizeof(float));
  float* CV_P = (float*)alloc(160 * sizeof(float));
  float* CV1  = (float*)alloc(416 * sizeof(float));
  const int isz[5] = {20480, 49152, 53248, 32768, 32768};
  ushort_t *HIs[5], *LOs[5];
  for (int s = 0; s < 5; ++s) {
    HIs[s] = (ushort_t*)alloc((size_t)isz[s] * 2);
    LOs[s] = (ushort_t*)alloc((size_t)isz[s] * 2);
  }

  hipMemsetAsync(OFF, 0, (size_t)(M + 1) * sizeof(int), stream);
  hipMemsetAsync(GSUM, 0, sizeof(float), stream);

  const int egrid = (E + 255) / 256;
  dim3 eg3(egrid, 3);
  k_count<<<eg3, 256, 0, stream>>>(ei_chem, ei_cond, ei_mol, OFF, E, N);
  k_geo<<<egrid, 256, 0, stream>>>(pos, ei_mol, GSUM, E);
  k_scanA<<<nblk, 256, 0, stream>>>(OFF, BSUM, M);
  k_scanB<<<1, 512, 0, stream>>>(BSUM, nblk, OFF, M);
  k_scanC<<<nblk, 256, 0, stream>>>(OFF, BSUM, WPOS, M);
  k_fill<<<eg3, 256, 0, stream>>>(ei_chem, ei_cond, ei_mol, WPOS, SRCS, E, N);

  S1Args s1{};
  for (int L = 0; L < 2; ++L) {
    const int b = (L == 0) ? 7 : 21;
    s1.Wc[L] = (const float*)d_in[b+0];  s1.as_c[L] = (const float*)d_in[b+1];
    s1.ad_c[L] = (const float*)d_in[b+2]; s1.bc[L] = (const float*)d_in[b+3];
    s1.Wd[L] = (const float*)d_in[b+4];  s1.as_d[L] = (const float*)d_in[b+5];
    s1.ad_d[L] = (const float*)d_in[b+6]; s1.bd[L] = (const float*)d_in[b+7];
    s1.Wm[L] = (const float*)d_in[b+8];  s1.as_m[L] = (const float*)d_in[b+9];
    s1.ad_m[L] = (const float*)d_in[b+10]; s1.bm[L] = (const float*)d_in[b+11];
    s1.Wl[L] = (const float*)d_in[b+12]; s1.bl[L] = (const float*)d_in[b+13];
  }
  s1.bp = (const float*)d_in[6];
  s1.WPP[0] = WPP0; s1.WPP[1] = WPP1;
  s1.BL[0] = BL0; s1.CL[0] = CL0; s1.BL[1] = BL1; s1.CL[1] = CL1;
  s1.BV_P = BV_P; s1.CV_P = CV_P; s1.CV1 = CV1;
  k_stage1<<<2, 256, 0, stream>>>(s1);
  k_stage2<<<12, 256, 0, stream>>>(Wp, WPP0, EXT_P);

  PackArgs pk{};
  pk.Wp = Wp; pk.EXT_P = EXT_P;
  pk.W1c = s1.Wc[0]; pk.W1d = s1.Wd[0]; pk.W1m = s1.Wm[0];
  pk.W2c = s1.Wc[1]; pk.W2d = s1.Wd[1]; pk.W2m = s1.Wm[1]; pk.WPP1 = WPP1;
  pk.Wl1 = s1.Wl[0]; pk.Wl2 = s1.Wl[1];
  for (int s = 0; s < 5; ++s) { pk.hi[s] = HIs[s]; pk.lo[s] = LOs[s]; }
  dim3 pg(32, 5);
  k_pack<<<pg, 256, 0, stream>>>(pk);

  const float gscale = 0.1f / (float)E;
  const int gx = (N + 255) / 256;
  const int gconv = (2 * N + 3) / 4;

  // h0 (+ layer-1 alphas) = x @ [Wp | Wp@W1''] + folds ; col-split 2x5nt
  k_proj<5><<<dim3(gx, 2), 256, 0, stream>>>(x, HIs[0], LOs[0], BV_P, CV_P, GSUM, gscale,
                                             10, 128, Hhi, Hlo, ALPHA, N);
  // layer 1: HT = h0@[W1c|W1d|W1m] (col-split 3x8nt) ; conv ; h1 via gmm2
  k_gemm1<8><<<dim3(gx, 3), 256, 0, stream>>>(Hhi, Hlo, HIs[1], LOs[1], CV1, GSUM, 0.f,
                                              24, 8, 384, HT, ALPHA, N);
  k_fconv<<<gconv, 256, 0, stream>>>(HT, ALPHA, SRCS, OFF, U, N);
  k_gmm2<<<gx, 256, 0, stream>>>(U, HIs[3], LOs[3], BL0, CL0, GSUM, gscale, Hhi, Hlo, N);
  // layer 2: HT = h1@[W2c|W2d|W2m] + layer-2 alphas (col-split 3x9nt)
  k_gemm1<9><<<dim3(gx, 3), 256, 0, stream>>>(Hhi, Hlo, HIs[2], LOs[2], CV1, GSUM, gscale,
                                              26, 9, 384, HT, ALPHA, N);
  k_fconv<<<gconv, 256, 0, stream>>>(HT, ALPHA, SRCS, OFF, U, N);
  k_gmm2<<<gx, 256, 0, stream>>>(U, HIs[4], LOs[4], BL1, CL1, GSUM, gscale, Hhi, Hlo, N);

  k_head<<<(N + 3) / 4, 256, 0, stream>>>(Hhi, Hlo, Wy, by, Wa, ba, (float*)d_out, N);
}